// Round 1
// baseline (2824.628 us; speedup 1.0000x reference)
//
#include <hip/hip_runtime.h>
#include <hip/hip_bf16.h>

// H=2, C=64, IN=128, EIN=64, N=50000, E=800000
constexpr int MAXD = 512;

__device__ __forceinline__ float lrelu(float v) { return v >= 0.f ? v : 0.2f * v; }

// ---------------- CSR build ----------------
__global__ void count_kernel(const int* __restrict__ dst, int* __restrict__ cnt, int E) {
    int e = blockIdx.x * blockDim.x + threadIdx.x;
    if (e < E) atomicAdd(&cnt[dst[e]], 1);
}

__global__ __launch_bounds__(1024) void scan_kernel(const int* __restrict__ cnt, int* __restrict__ rowptr, int n) {
    __shared__ int part[1024];
    int t = threadIdx.x;
    int CH = (n + 1023) / 1024;
    int base = t * CH;
    int local = 0;
    for (int i = 0; i < CH; i++) { int idx = base + i; if (idx < n) local += cnt[idx]; }
    part[t] = local;
    __syncthreads();
    for (int o = 1; o < 1024; o <<= 1) {
        int v = (t >= o) ? part[t - o] : 0;
        __syncthreads();
        part[t] += v;
        __syncthreads();
    }
    int run = part[t] - local;  // exclusive prefix
    for (int i = 0; i < CH; i++) {
        int idx = base + i;
        if (idx < n) { rowptr[idx] = run; run += cnt[idx]; }
    }
    if (t == 1023) rowptr[n] = run;
}

__global__ void scatter_kernel(const int* __restrict__ src, const int* __restrict__ dst,
                               int* __restrict__ cursor, int* __restrict__ ssrc, int E) {
    int e = blockIdx.x * blockDim.x + threadIdx.x;
    if (e < E) {
        int pos = atomicAdd(&cursor[dst[e]], 1);
        ssrc[pos] = src[e];
    }
}

// ---------------- fold: M = We_fold @ Wde, b0 = be@Wde + bde ----------------
__global__ void fold_kernel(const float* __restrict__ We, const float* __restrict__ Wde,
                            const float* __restrict__ be, const float* __restrict__ bde,
                            float* __restrict__ M, float* __restrict__ b0) {
    int j = threadIdx.x;  // 0..63
    int k = blockIdx.x;   // 0..64; block 64 does b0
    if (k < 64) {
        float s = 0.f;
        for (int c = 0; c < 64; c++)
            s = fmaf(0.5f * (We[k * 128 + c] + We[k * 128 + 64 + c]), Wde[c * 64 + j], s);
        M[k * 64 + j] = s;
    } else {
        float s = bde[j];
        for (int c = 0; c < 64; c++) s = fmaf(be[c], Wde[c * 64 + j], s);
        b0[j] = s;
    }
}

// ---------------- encoder: one head per thread (h = blockIdx.y) ----------------
template <int K>
__global__ __launch_bounds__(256) void enc_gemm(const float* __restrict__ X, const float* __restrict__ W,
                                                const float* __restrict__ avs, const float* __restrict__ avd,
                                                float* __restrict__ xw, float* __restrict__ a_s,
                                                float* __restrict__ a_d, int Nn) {
    int n = blockIdx.x * 256 + threadIdx.x;
    int h = blockIdx.y;
    if (n >= Nn) return;
    const float* xr = X + (size_t)n * K;
    float acc[64];
#pragma unroll
    for (int j = 0; j < 64; j++) acc[j] = 0.f;
    for (int kc = 0; kc < K; kc += 16) {
        float xv[16];
#pragma unroll
        for (int i = 0; i < 16; i += 4) {
            float4 t = *(const float4*)(xr + kc + i);
            xv[i] = t.x; xv[i + 1] = t.y; xv[i + 2] = t.z; xv[i + 3] = t.w;
        }
#pragma unroll
        for (int k = 0; k < 16; k++) {
            const float* wr = W + (size_t)(kc + k) * 128 + h * 64;
#pragma unroll
            for (int j = 0; j < 64; j++) acc[j] = fmaf(xv[k], wr[j], acc[j]);
        }
    }
    float as = 0.f, ad = 0.f;
    const float* vs = avs + h * 64;
    const float* vd = avd + h * 64;
#pragma unroll
    for (int j = 0; j < 64; j++) { as = fmaf(acc[j], vs[j], as); ad = fmaf(acc[j], vd[j], ad); }
    float* xwr = xw + (size_t)n * 128 + h * 64;
#pragma unroll
    for (int j = 0; j < 64; j += 4) {
        float4 t = {acc[j], acc[j + 1], acc[j + 2], acc[j + 3]};
        *(float4*)(xwr + j) = t;
    }
    a_s[n * 2 + h] = as;
    a_d[n * 2 + h] = ad;
}

// ---------------- row-map: out[r,:] = A[r,:] @ M + b0   (A is [R,64], M is [64,OD]) ----------
// v2: A row hoisted into registers ONCE (16 float4 = 64 VGPRs); output columns processed in
// explicit chunks of 32 (acc[32] live) so peak pressure ~110 VGPRs -> 4 waves/SIMD, and the
// compiler cannot strip-mine into an A-re-reading form (previous codegen: VGPR_Count=56,
// j blocked at 16, 4x L1 re-reads, VALUBusy 29%). M stays wave-uniform -> SGPR loads.
template <int OD>
__global__ __launch_bounds__(256, 4) void rowmap_kernel(const float* __restrict__ A, const float* __restrict__ M,
                                                        const float* __restrict__ b0, float* __restrict__ out, int R) {
    int r = blockIdx.x * 256 + threadIdx.x;
    if (r >= R) return;
    const float* ar = A + (size_t)r * 64;
    float4 xv[16];
#pragma unroll
    for (int i = 0; i < 16; i++) xv[i] = *(const float4*)(ar + i * 4);
    float* orow = out + (size_t)r * OD;
#pragma unroll 1
    for (int jc = 0; jc < OD; jc += 32) {
        float acc[32];
#pragma unroll
        for (int j = 0; j < 32; j++) acc[j] = b0[jc + j];
#pragma unroll
        for (int kq = 0; kq < 16; kq++) {
            float4 xf = xv[kq];
            const float* m0 = M + (size_t)(kq * 4) * OD + jc;
            const float* m1 = m0 + OD;
            const float* m2 = m1 + OD;
            const float* m3 = m2 + OD;
#pragma unroll
            for (int j = 0; j < 32; j++) acc[j] = fmaf(xf.x, m0[j], acc[j]);
#pragma unroll
            for (int j = 0; j < 32; j++) acc[j] = fmaf(xf.y, m1[j], acc[j]);
#pragma unroll
            for (int j = 0; j < 32; j++) acc[j] = fmaf(xf.z, m2[j], acc[j]);
#pragma unroll
            for (int j = 0; j < 32; j++) acc[j] = fmaf(xf.w, m3[j], acc[j]);
        }
#pragma unroll
        for (int j = 0; j < 32; j += 4) {
            float4 t = {acc[j], acc[j + 1], acc[j + 2], acc[j + 3]};
            *(float4*)(orow + jc + j) = t;
        }
    }
}

// ---------------- fused message passing for BOTH convs; outputs head-mean hm ----------------
__global__ __launch_bounds__(128) void msg_fused(
    const float* __restrict__ xw_n, const float* __restrict__ a_sn, const float* __restrict__ a_dn,
    const float* __restrict__ xw_e, const float* __restrict__ a_se, const float* __restrict__ a_de,
    const int* __restrict__ rowptr, const int* __restrict__ ssrc,
    const float* __restrict__ bn, const float* __restrict__ be,
    float* __restrict__ hm_n, float* __restrict__ hm_e) {
    int n = blockIdx.x;
    int tid = threadIdx.x;
    int h = tid >> 6, c = tid & 63;
    __shared__ int s_src[MAXD];
    __shared__ float t_n[2][MAXD];
    __shared__ float t_e[2][MAXD];
    __shared__ float red[8];  // [conv*4 + {m0,m1,d0,d1}]
    __shared__ float hsh[2][128];

    int base = rowptr[n];
    int deg = rowptr[n + 1] - base;
    int degc = min(deg, MAXD);

    float adn0 = a_dn[n * 2 + 0], adn1 = a_dn[n * 2 + 1];
    float ade0 = a_de[n * 2 + 0], ade1 = a_de[n * 2 + 1];
    float2 asn_n = *(const float2*)(a_sn + (size_t)n * 2);
    float2 ase_n = *(const float2*)(a_se + (size_t)n * 2);
    float es_n0 = lrelu(asn_n.x + adn0), es_n1 = lrelu(asn_n.y + adn1);
    float es_e0 = lrelu(ase_n.x + ade0), es_e1 = lrelu(ase_n.y + ade1);

    // pass 1: cache src indices + leaky-relu logits (ONE gather over a_s)
    for (int i = tid; i < degc; i += 128) {
        int s = ssrc[base + i];
        s_src[i] = s;
        float2 an = *(const float2*)(a_sn + (size_t)s * 2);
        float2 ae = *(const float2*)(a_se + (size_t)s * 2);
        t_n[0][i] = lrelu(an.x + adn0);
        t_n[1][i] = lrelu(an.y + adn1);
        t_e[0][i] = lrelu(ae.x + ade0);
        t_e[1][i] = lrelu(ae.y + ade1);
    }
    __syncthreads();

    // reductions: wave 0 -> conv n, wave 1 -> conv e (both heads per wave)
    int w = tid >> 6;
    int lane = tid & 63;
    {
        const float(*tt)[MAXD] = w ? t_e : t_n;
        const float* asx = w ? a_se : a_sn;
        float ad0 = w ? ade0 : adn0, ad1 = w ? ade1 : adn1;
        float es0 = w ? es_e0 : es_n0, es1 = w ? es_e1 : es_n1;
        float m0 = es0, m1 = es1;
        for (int i = lane; i < degc; i += 64) { m0 = fmaxf(m0, tt[0][i]); m1 = fmaxf(m1, tt[1][i]); }
        for (int i = MAXD + lane; i < deg; i += 64) {
            int s = ssrc[base + i];
            float2 a = *(const float2*)(asx + (size_t)s * 2);
            m0 = fmaxf(m0, lrelu(a.x + ad0)); m1 = fmaxf(m1, lrelu(a.y + ad1));
        }
#pragma unroll
        for (int o = 1; o < 64; o <<= 1) { m0 = fmaxf(m0, __shfl_xor(m0, o)); m1 = fmaxf(m1, __shfl_xor(m1, o)); }
        // denominator: edge terms reduced across lanes; self term added ONCE after reduction
        float d0 = 0.f, d1 = 0.f;
        for (int i = lane; i < degc; i += 64) { d0 += __expf(tt[0][i] - m0); d1 += __expf(tt[1][i] - m1); }
        for (int i = MAXD + lane; i < deg; i += 64) {
            int s = ssrc[base + i];
            float2 a = *(const float2*)(asx + (size_t)s * 2);
            d0 += __expf(lrelu(a.x + ad0) - m0); d1 += __expf(lrelu(a.y + ad1) - m1);
        }
#pragma unroll
        for (int o = 1; o < 64; o <<= 1) { d0 += __shfl_xor(d0, o); d1 += __shfl_xor(d1, o); }
        d0 += __expf(es0 - m0);  // self-loop contribution, exactly once
        d1 += __expf(es1 - m1);
        if (lane == 0) { red[w * 4 + 0] = m0; red[w * 4 + 1] = m1; red[w * 4 + 2] = d0; red[w * 4 + 3] = d1; }
    }
    __syncthreads();

    // convert logits -> unnormalized weights in LDS (once)
    for (int i = tid; i < degc; i += 128) {
        t_n[0][i] = __expf(t_n[0][i] - red[0]);
        t_n[1][i] = __expf(t_n[1][i] - red[1]);
        t_e[0][i] = __expf(t_e[0][i] - red[4]);
        t_e[1][i] = __expf(t_e[1][i] - red[5]);
    }
    __syncthreads();

    float mn = red[h], dn_ = red[2 + h];
    float me = red[4 + h], de_ = red[6 + h];
    float accn = __expf((h ? es_n1 : es_n0) - mn) * xw_n[(size_t)n * 128 + h * 64 + c];
    float acce = __expf((h ? es_e1 : es_e0) - me) * xw_e[(size_t)n * 128 + h * 64 + c];
    for (int i = 0; i < degc; i++) {
        int s = s_src[i];
        float wn_ = t_n[h][i];
        float we_ = t_e[h][i];
        accn = fmaf(wn_, xw_n[(size_t)s * 128 + h * 64 + c], accn);
        acce = fmaf(we_, xw_e[(size_t)s * 128 + h * 64 + c], acce);
    }
    for (int i = MAXD; i < deg; i++) {
        int s = ssrc[base + i];
        float2 an = *(const float2*)(a_sn + (size_t)s * 2);
        float2 ae = *(const float2*)(a_se + (size_t)s * 2);
        float tn_ = lrelu(h ? (an.y + adn1) : (an.x + adn0));
        float te_ = lrelu(h ? (ae.y + ade1) : (ae.x + ade0));
        accn = fmaf(__expf(tn_ - mn), xw_n[(size_t)s * 128 + h * 64 + c], accn);
        acce = fmaf(__expf(te_ - me), xw_e[(size_t)s * 128 + h * 64 + c], acce);
    }
    hsh[0][tid] = accn / dn_;
    hsh[1][tid] = acce / de_;
    __syncthreads();
    if (tid < 64) {
        hm_n[(size_t)n * 64 + tid] = fmaf(0.5f, hsh[0][tid] + hsh[0][64 + tid], bn[tid]);
        hm_e[(size_t)n * 64 + tid] = fmaf(0.5f, hsh[1][tid] + hsh[1][64 + tid], be[tid]);
    }
}

extern "C" void kernel_launch(void* const* d_in, const int* in_sizes, int n_in,
                              void* d_out, int out_size, void* d_ws, size_t ws_size,
                              hipStream_t stream) {
    const float* x   = (const float*)d_in[0];
    const float* xe  = (const float*)d_in[1];
    const int*   ei  = (const int*)d_in[2];
    const float* Wn  = (const float*)d_in[3];
    const float* asn = (const float*)d_in[4];
    const float* adn = (const float*)d_in[5];
    const float* bn  = (const float*)d_in[6];
    const float* We  = (const float*)d_in[7];
    const float* ase = (const float*)d_in[8];
    const float* ade = (const float*)d_in[9];
    const float* be  = (const float*)d_in[10];
    const float* Wdx = (const float*)d_in[11];
    const float* bdx = (const float*)d_in[12];
    const float* Wde = (const float*)d_in[13];
    const float* bde = (const float*)d_in[14];

    const int N  = in_sizes[0] / 128;  // 50000
    const int NE = in_sizes[1] / 64;   // 800000
    const int E  = in_sizes[2] / 2;    // 800000
    const int* src = ei;
    const int* dst = ei + E;

    char* wsb = (char*)d_ws;
    size_t off = 0;
    auto alloc = [&](size_t bytes) -> void* {
        void* p = wsb + off;
        off += (bytes + 255) & ~(size_t)255;
        return p;
    };
    float* xw_n = (float*)alloc((size_t)N * 128 * 4);
    float* a_sn = (float*)alloc((size_t)N * 2 * 4);
    float* a_dn = (float*)alloc((size_t)N * 2 * 4);
    float* xw_e = (float*)alloc((size_t)N * 128 * 4);
    float* a_se = (float*)alloc((size_t)N * 2 * 4);
    float* a_de = (float*)alloc((size_t)N * 2 * 4);
    float* hm_n = (float*)alloc((size_t)N * 64 * 4);
    float* hm_e = (float*)alloc((size_t)N * 64 * 4);
    float* Mt   = (float*)alloc((size_t)64 * 64 * 4);
    float* b0t  = (float*)alloc((size_t)64 * 4);
    int* cnt    = (int*)alloc((size_t)(N + 1) * 4);
    int* rowptr = (int*)alloc((size_t)(N + 1) * 4);
    int* cursor = (int*)alloc((size_t)(N + 1) * 4);
    int* ssrc   = (int*)alloc((size_t)E * 4);

    float* x_rec = (float*)d_out;
    float* e_rec = (float*)d_out + (size_t)N * 128;

    // CSR build (shared by both convs)
    hipMemsetAsync(cnt, 0, (size_t)N * 4, stream);
    count_kernel<<<(E + 255) / 256, 256, 0, stream>>>(dst, cnt, E);
    scan_kernel<<<1, 1024, 0, stream>>>(cnt, rowptr, N);
    hipMemcpyAsync(cursor, rowptr, (size_t)N * 4, hipMemcpyDeviceToDevice, stream);
    scatter_kernel<<<(E + 255) / 256, 256, 0, stream>>>(src, dst, cursor, ssrc, E);

    // Fold tail affine map
    fold_kernel<<<65, 64, 0, stream>>>(We, Wde, be, bde, Mt, b0t);

    // Encoders (one head per thread)
    enc_gemm<128><<<dim3((N + 255) / 256, 2), 256, 0, stream>>>(x, Wn, asn, adn, xw_n, a_sn, a_dn, N);
    enc_gemm<64><<<dim3((N + 255) / 256, 2), 256, 0, stream>>>(xe, We, ase, ade, xw_e, a_se, a_de, N);

    // Tail: 750k self-loop-only rows, folded to a single affine map
    rowmap_kernel<64><<<(NE - N + 255) / 256, 256, 0, stream>>>(xe + (size_t)N * 64, Mt, b0t,
                                                                e_rec + (size_t)N * 64, NE - N);

    // Fused message passing for both convs -> head-mean hidden states
    msg_fused<<<N, 128, 0, stream>>>(xw_n, a_sn, a_dn, xw_e, a_se, a_de, rowptr, ssrc, bn, be, hm_n, hm_e);

    // Decoders
    rowmap_kernel<128><<<(N + 255) / 256, 256, 0, stream>>>(hm_n, Wdx, bdx, x_rec, N);
    rowmap_kernel<64><<<(N + 255) / 256, 256, 0, stream>>>(hm_e, Wde, bde, e_rec, N);
}

// Round 2
// 1252.936 us; speedup vs baseline: 2.2544x; 2.2544x over previous
//
#include <hip/hip_runtime.h>
#include <hip/hip_bf16.h>

// H=2, C=64, IN=128, EIN=64, N=50000, E=800000
constexpr int MAXD = 512;

__device__ __forceinline__ float lrelu(float v) { return v >= 0.f ? v : 0.2f * v; }

// ---------------- CSR build ----------------
__global__ void count_kernel(const int* __restrict__ dst, int* __restrict__ cnt, int E) {
    int e = blockIdx.x * blockDim.x + threadIdx.x;
    if (e < E) atomicAdd(&cnt[dst[e]], 1);
}

__global__ __launch_bounds__(1024) void scan_kernel(const int* __restrict__ cnt, int* __restrict__ rowptr, int n) {
    __shared__ int part[1024];
    int t = threadIdx.x;
    int CH = (n + 1023) / 1024;
    int base = t * CH;
    int local = 0;
    for (int i = 0; i < CH; i++) { int idx = base + i; if (idx < n) local += cnt[idx]; }
    part[t] = local;
    __syncthreads();
    for (int o = 1; o < 1024; o <<= 1) {
        int v = (t >= o) ? part[t - o] : 0;
        __syncthreads();
        part[t] += v;
        __syncthreads();
    }
    int run = part[t] - local;  // exclusive prefix
    for (int i = 0; i < CH; i++) {
        int idx = base + i;
        if (idx < n) { rowptr[idx] = run; run += cnt[idx]; }
    }
    if (t == 1023) rowptr[n] = run;
}

__global__ void scatter_kernel(const int* __restrict__ src, const int* __restrict__ dst,
                               int* __restrict__ cursor, int* __restrict__ ssrc, int E) {
    int e = blockIdx.x * blockDim.x + threadIdx.x;
    if (e < E) {
        int pos = atomicAdd(&cursor[dst[e]], 1);
        ssrc[pos] = src[e];
    }
}

// ---------------- fold: M = We_fold @ Wde, b0 = be@Wde + bde ----------------
__global__ void fold_kernel(const float* __restrict__ We, const float* __restrict__ Wde,
                            const float* __restrict__ be, const float* __restrict__ bde,
                            float* __restrict__ M, float* __restrict__ b0) {
    int j = threadIdx.x;  // 0..63
    int k = blockIdx.x;   // 0..64; block 64 does b0
    if (k < 64) {
        float s = 0.f;
        for (int c = 0; c < 64; c++)
            s = fmaf(0.5f * (We[k * 128 + c] + We[k * 128 + 64 + c]), Wde[c * 64 + j], s);
        M[k * 64 + j] = s;
    } else {
        float s = bde[j];
        for (int c = 0; c < 64; c++) s = fmaf(be[c], Wde[c * 64 + j], s);
        b0[j] = s;
    }
}

// ---------------- encoder: one head per thread (h = blockIdx.y) ----------------
template <int K>
__global__ __launch_bounds__(256) void enc_gemm(const float* __restrict__ X, const float* __restrict__ W,
                                                const float* __restrict__ avs, const float* __restrict__ avd,
                                                float* __restrict__ xw, float* __restrict__ a_s,
                                                float* __restrict__ a_d, int Nn) {
    int n = blockIdx.x * 256 + threadIdx.x;
    int h = blockIdx.y;
    if (n >= Nn) return;
    const float* xr = X + (size_t)n * K;
    float acc[64];
#pragma unroll
    for (int j = 0; j < 64; j++) acc[j] = 0.f;
    for (int kc = 0; kc < K; kc += 16) {
        float xv[16];
#pragma unroll
        for (int i = 0; i < 16; i += 4) {
            float4 t = *(const float4*)(xr + kc + i);
            xv[i] = t.x; xv[i + 1] = t.y; xv[i + 2] = t.z; xv[i + 3] = t.w;
        }
#pragma unroll
        for (int k = 0; k < 16; k++) {
            const float* wr = W + (size_t)(kc + k) * 128 + h * 64;
#pragma unroll
            for (int j = 0; j < 64; j++) acc[j] = fmaf(xv[k], wr[j], acc[j]);
        }
    }
    float as = 0.f, ad = 0.f;
    const float* vs = avs + h * 64;
    const float* vd = avd + h * 64;
#pragma unroll
    for (int j = 0; j < 64; j++) { as = fmaf(acc[j], vs[j], as); ad = fmaf(acc[j], vd[j], ad); }
    float* xwr = xw + (size_t)n * 128 + h * 64;
#pragma unroll
    for (int j = 0; j < 64; j += 4) {
        float4 t = {acc[j], acc[j + 1], acc[j + 2], acc[j + 3]};
        *(float4*)(xwr + j) = t;
    }
    a_s[n * 2 + h] = as;
    a_d[n * 2 + h] = ad;
}

// ---------------- row-map: out[r,:] = A[r,:] @ M + b0   (A is [R,64], M is [64,OD]) ----------
// v3 column-per-lane: lane j owns output column (jc+j); M[:,jc+j] lives in 64 VGPRs (all
// indices compile-time after unroll -> guaranteed registers, no spill). The A-row pointer is
// wave-uniform (readfirstlane) so each float4 read is a 1-cacheline broadcast instead of the
// old 64-cacheline strided wave access (v1 pathology: 31% HBM, 29% VALU, transaction-bound).
// Stores are lane-contiguous 256B. 4 partial accumulators + 2-row unroll break the FMA chain.
template <int OD>
__global__ __launch_bounds__(256) void rowmap_kernel(const float* __restrict__ A, const float* __restrict__ M,
                                                     const float* __restrict__ b0, float* __restrict__ out, int R) {
    constexpr int RPW = 32;  // rows per wave
    int lane = threadIdx.x & 63;
    int wave = threadIdx.x >> 6;
    int jc = blockIdx.y * 64;
    int row0 = (blockIdx.x * 4 + wave) * RPW;
    if (row0 >= R) return;
    float mc[64];
#pragma unroll
    for (int k = 0; k < 64; k++) mc[k] = M[(size_t)k * OD + jc + lane];
    float b0v = b0[jc + lane];
    int rend = min(row0 + RPW, R);
    for (int r = row0; r < rend; r += 2) {
        int r_u = __builtin_amdgcn_readfirstlane(r);
        bool two = (r_u + 1 < rend);
        const float* ar0 = A + (size_t)r_u * 64;
        const float* ar1 = ar0 + (two ? 64 : 0);
        float a00 = b0v, a01 = 0.f, a02 = 0.f, a03 = 0.f;
        float a10 = b0v, a11 = 0.f, a12 = 0.f, a13 = 0.f;
#pragma unroll
        for (int kk = 0; kk < 16; kk++) {
            float4 av0 = *(const float4*)(ar0 + kk * 4);
            float4 av1 = *(const float4*)(ar1 + kk * 4);
            a00 = fmaf(av0.x, mc[4 * kk + 0], a00);
            a01 = fmaf(av0.y, mc[4 * kk + 1], a01);
            a02 = fmaf(av0.z, mc[4 * kk + 2], a02);
            a03 = fmaf(av0.w, mc[4 * kk + 3], a03);
            a10 = fmaf(av1.x, mc[4 * kk + 0], a10);
            a11 = fmaf(av1.y, mc[4 * kk + 1], a11);
            a12 = fmaf(av1.z, mc[4 * kk + 2], a12);
            a13 = fmaf(av1.w, mc[4 * kk + 3], a13);
        }
        out[(size_t)r_u * OD + jc + lane] = (a00 + a01) + (a02 + a03);
        if (two) out[((size_t)r_u + 1) * OD + jc + lane] = (a10 + a11) + (a12 + a13);
    }
}

// ---------------- fused message passing for BOTH convs; outputs head-mean hm ----------------
__global__ __launch_bounds__(128) void msg_fused(
    const float* __restrict__ xw_n, const float* __restrict__ a_sn, const float* __restrict__ a_dn,
    const float* __restrict__ xw_e, const float* __restrict__ a_se, const float* __restrict__ a_de,
    const int* __restrict__ rowptr, const int* __restrict__ ssrc,
    const float* __restrict__ bn, const float* __restrict__ be,
    float* __restrict__ hm_n, float* __restrict__ hm_e) {
    int n = blockIdx.x;
    int tid = threadIdx.x;
    int h = tid >> 6, c = tid & 63;
    __shared__ int s_src[MAXD];
    __shared__ float t_n[2][MAXD];
    __shared__ float t_e[2][MAXD];
    __shared__ float red[8];  // [conv*4 + {m0,m1,d0,d1}]
    __shared__ float hsh[2][128];

    int base = rowptr[n];
    int deg = rowptr[n + 1] - base;
    int degc = min(deg, MAXD);

    float adn0 = a_dn[n * 2 + 0], adn1 = a_dn[n * 2 + 1];
    float ade0 = a_de[n * 2 + 0], ade1 = a_de[n * 2 + 1];
    float2 asn_n = *(const float2*)(a_sn + (size_t)n * 2);
    float2 ase_n = *(const float2*)(a_se + (size_t)n * 2);
    float es_n0 = lrelu(asn_n.x + adn0), es_n1 = lrelu(asn_n.y + adn1);
    float es_e0 = lrelu(ase_n.x + ade0), es_e1 = lrelu(ase_n.y + ade1);

    // pass 1: cache src indices + leaky-relu logits (ONE gather over a_s)
    for (int i = tid; i < degc; i += 128) {
        int s = ssrc[base + i];
        s_src[i] = s;
        float2 an = *(const float2*)(a_sn + (size_t)s * 2);
        float2 ae = *(const float2*)(a_se + (size_t)s * 2);
        t_n[0][i] = lrelu(an.x + adn0);
        t_n[1][i] = lrelu(an.y + adn1);
        t_e[0][i] = lrelu(ae.x + ade0);
        t_e[1][i] = lrelu(ae.y + ade1);
    }
    __syncthreads();

    // reductions: wave 0 -> conv n, wave 1 -> conv e (both heads per wave)
    int w = tid >> 6;
    int lane = tid & 63;
    {
        const float(*tt)[MAXD] = w ? t_e : t_n;
        const float* asx = w ? a_se : a_sn;
        float ad0 = w ? ade0 : adn0, ad1 = w ? ade1 : adn1;
        float es0 = w ? es_e0 : es_n0, es1 = w ? es_e1 : es_n1;
        float m0 = es0, m1 = es1;
        for (int i = lane; i < degc; i += 64) { m0 = fmaxf(m0, tt[0][i]); m1 = fmaxf(m1, tt[1][i]); }
        for (int i = MAXD + lane; i < deg; i += 64) {
            int s = ssrc[base + i];
            float2 a = *(const float2*)(asx + (size_t)s * 2);
            m0 = fmaxf(m0, lrelu(a.x + ad0)); m1 = fmaxf(m1, lrelu(a.y + ad1));
        }
#pragma unroll
        for (int o = 1; o < 64; o <<= 1) { m0 = fmaxf(m0, __shfl_xor(m0, o)); m1 = fmaxf(m1, __shfl_xor(m1, o)); }
        // denominator: edge terms reduced across lanes; self term added ONCE after reduction
        float d0 = 0.f, d1 = 0.f;
        for (int i = lane; i < degc; i += 64) { d0 += __expf(tt[0][i] - m0); d1 += __expf(tt[1][i] - m1); }
        for (int i = MAXD + lane; i < deg; i += 64) {
            int s = ssrc[base + i];
            float2 a = *(const float2*)(asx + (size_t)s * 2);
            d0 += __expf(lrelu(a.x + ad0) - m0); d1 += __expf(lrelu(a.y + ad1) - m1);
        }
#pragma unroll
        for (int o = 1; o < 64; o <<= 1) { d0 += __shfl_xor(d0, o); d1 += __shfl_xor(d1, o); }
        d0 += __expf(es0 - m0);  // self-loop contribution, exactly once
        d1 += __expf(es1 - m1);
        if (lane == 0) { red[w * 4 + 0] = m0; red[w * 4 + 1] = m1; red[w * 4 + 2] = d0; red[w * 4 + 3] = d1; }
    }
    __syncthreads();

    // convert logits -> unnormalized weights in LDS (once)
    for (int i = tid; i < degc; i += 128) {
        t_n[0][i] = __expf(t_n[0][i] - red[0]);
        t_n[1][i] = __expf(t_n[1][i] - red[1]);
        t_e[0][i] = __expf(t_e[0][i] - red[4]);
        t_e[1][i] = __expf(t_e[1][i] - red[5]);
    }
    __syncthreads();

    float mn = red[h], dn_ = red[2 + h];
    float me = red[4 + h], de_ = red[6 + h];
    float accn = __expf((h ? es_n1 : es_n0) - mn) * xw_n[(size_t)n * 128 + h * 64 + c];
    float acce = __expf((h ? es_e1 : es_e0) - me) * xw_e[(size_t)n * 128 + h * 64 + c];
    for (int i = 0; i < degc; i++) {
        int s = s_src[i];
        float wn_ = t_n[h][i];
        float we_ = t_e[h][i];
        accn = fmaf(wn_, xw_n[(size_t)s * 128 + h * 64 + c], accn);
        acce = fmaf(we_, xw_e[(size_t)s * 128 + h * 64 + c], acce);
    }
    for (int i = MAXD; i < deg; i++) {
        int s = ssrc[base + i];
        float2 an = *(const float2*)(a_sn + (size_t)s * 2);
        float2 ae = *(const float2*)(a_se + (size_t)s * 2);
        float tn_ = lrelu(h ? (an.y + adn1) : (an.x + adn0));
        float te_ = lrelu(h ? (ae.y + ade1) : (ae.x + ade0));
        accn = fmaf(__expf(tn_ - mn), xw_n[(size_t)s * 128 + h * 64 + c], accn);
        acce = fmaf(__expf(te_ - me), xw_e[(size_t)s * 128 + h * 64 + c], acce);
    }
    hsh[0][tid] = accn / dn_;
    hsh[1][tid] = acce / de_;
    __syncthreads();
    if (tid < 64) {
        hm_n[(size_t)n * 64 + tid] = fmaf(0.5f, hsh[0][tid] + hsh[0][64 + tid], bn[tid]);
        hm_e[(size_t)n * 64 + tid] = fmaf(0.5f, hsh[1][tid] + hsh[1][64 + tid], be[tid]);
    }
}

extern "C" void kernel_launch(void* const* d_in, const int* in_sizes, int n_in,
                              void* d_out, int out_size, void* d_ws, size_t ws_size,
                              hipStream_t stream) {
    const float* x   = (const float*)d_in[0];
    const float* xe  = (const float*)d_in[1];
    const int*   ei  = (const int*)d_in[2];
    const float* Wn  = (const float*)d_in[3];
    const float* asn = (const float*)d_in[4];
    const float* adn = (const float*)d_in[5];
    const float* bn  = (const float*)d_in[6];
    const float* We  = (const float*)d_in[7];
    const float* ase = (const float*)d_in[8];
    const float* ade = (const float*)d_in[9];
    const float* be  = (const float*)d_in[10];
    const float* Wdx = (const float*)d_in[11];
    const float* bdx = (const float*)d_in[12];
    const float* Wde = (const float*)d_in[13];
    const float* bde = (const float*)d_in[14];

    const int N  = in_sizes[0] / 128;  // 50000
    const int NE = in_sizes[1] / 64;   // 800000
    const int E  = in_sizes[2] / 2;    // 800000
    const int* src = ei;
    const int* dst = ei + E;

    char* wsb = (char*)d_ws;
    size_t off = 0;
    auto alloc = [&](size_t bytes) -> void* {
        void* p = wsb + off;
        off += (bytes + 255) & ~(size_t)255;
        return p;
    };
    float* xw_n = (float*)alloc((size_t)N * 128 * 4);
    float* a_sn = (float*)alloc((size_t)N * 2 * 4);
    float* a_dn = (float*)alloc((size_t)N * 2 * 4);
    float* xw_e = (float*)alloc((size_t)N * 128 * 4);
    float* a_se = (float*)alloc((size_t)N * 2 * 4);
    float* a_de = (float*)alloc((size_t)N * 2 * 4);
    float* hm_n = (float*)alloc((size_t)N * 64 * 4);
    float* hm_e = (float*)alloc((size_t)N * 64 * 4);
    float* Mt   = (float*)alloc((size_t)64 * 64 * 4);
    float* b0t  = (float*)alloc((size_t)64 * 4);
    int* cnt    = (int*)alloc((size_t)(N + 1) * 4);
    int* rowptr = (int*)alloc((size_t)(N + 1) * 4);
    int* cursor = (int*)alloc((size_t)(N + 1) * 4);
    int* ssrc   = (int*)alloc((size_t)E * 4);

    float* x_rec = (float*)d_out;
    float* e_rec = (float*)d_out + (size_t)N * 128;

    // CSR build (shared by both convs)
    hipMemsetAsync(cnt, 0, (size_t)N * 4, stream);
    count_kernel<<<(E + 255) / 256, 256, 0, stream>>>(dst, cnt, E);
    scan_kernel<<<1, 1024, 0, stream>>>(cnt, rowptr, N);
    hipMemcpyAsync(cursor, rowptr, (size_t)N * 4, hipMemcpyDeviceToDevice, stream);
    scatter_kernel<<<(E + 255) / 256, 256, 0, stream>>>(src, dst, cursor, ssrc, E);

    // Fold tail affine map
    fold_kernel<<<65, 64, 0, stream>>>(We, Wde, be, bde, Mt, b0t);

    // Encoders (one head per thread)
    enc_gemm<128><<<dim3((N + 255) / 256, 2), 256, 0, stream>>>(x, Wn, asn, adn, xw_n, a_sn, a_dn, N);
    enc_gemm<64><<<dim3((N + 255) / 256, 2), 256, 0, stream>>>(xe, We, ase, ade, xw_e, a_se, a_de, N);

    // Tail: 750k self-loop-only rows, folded to a single affine map (col-per-lane rowmap)
    {
        int R = NE - N;
        rowmap_kernel<64><<<dim3((R + 127) / 128, 1), 256, 0, stream>>>(
            xe + (size_t)N * 64, Mt, b0t, e_rec + (size_t)N * 64, R);
    }

    // Fused message passing for both convs -> head-mean hidden states
    msg_fused<<<N, 128, 0, stream>>>(xw_n, a_sn, a_dn, xw_e, a_se, a_de, rowptr, ssrc, bn, be, hm_n, hm_e);

    // Decoders (col-per-lane rowmap; OD=128 splits column halves across gridDim.y)
    rowmap_kernel<128><<<dim3((N + 127) / 128, 2), 256, 0, stream>>>(hm_n, Wdx, bdx, x_rec, N);
    rowmap_kernel<64><<<dim3((N + 127) / 128, 1), 256, 0, stream>>>(hm_e, Wde, bde, e_rec, N);
}

// Round 3
// 1149.384 us; speedup vs baseline: 2.4575x; 1.0901x over previous
//
#include <hip/hip_runtime.h>
#include <hip/hip_bf16.h>

// H=2, C=64, IN=128, EIN=64, N=50000, E=800000
constexpr int MAXD = 512;

__device__ __forceinline__ float lrelu(float v) { return v >= 0.f ? v : 0.2f * v; }

// ---------------- CSR build ----------------
__global__ void count_kernel(const int* __restrict__ dst, int* __restrict__ cnt, int E) {
    int e = blockIdx.x * blockDim.x + threadIdx.x;
    if (e < E) atomicAdd(&cnt[dst[e]], 1);
}

__global__ __launch_bounds__(1024) void scan_kernel(const int* __restrict__ cnt, int* __restrict__ rowptr, int n) {
    __shared__ int part[1024];
    int t = threadIdx.x;
    int CH = (n + 1023) / 1024;
    int base = t * CH;
    int local = 0;
    for (int i = 0; i < CH; i++) { int idx = base + i; if (idx < n) local += cnt[idx]; }
    part[t] = local;
    __syncthreads();
    for (int o = 1; o < 1024; o <<= 1) {
        int v = (t >= o) ? part[t - o] : 0;
        __syncthreads();
        part[t] += v;
        __syncthreads();
    }
    int run = part[t] - local;  // exclusive prefix
    for (int i = 0; i < CH; i++) {
        int idx = base + i;
        if (idx < n) { rowptr[idx] = run; run += cnt[idx]; }
    }
    if (t == 1023) rowptr[n] = run;
}

__global__ void scatter_kernel(const int* __restrict__ src, const int* __restrict__ dst,
                               int* __restrict__ cursor, int* __restrict__ ssrc, int E) {
    int e = blockIdx.x * blockDim.x + threadIdx.x;
    if (e < E) {
        int pos = atomicAdd(&cursor[dst[e]], 1);
        ssrc[pos] = src[e];
    }
}

// ---------------- fold: M = We_fold @ Wde, b0 = be@Wde + bde ----------------
__global__ void fold_kernel(const float* __restrict__ We, const float* __restrict__ Wde,
                            const float* __restrict__ be, const float* __restrict__ bde,
                            float* __restrict__ M, float* __restrict__ b0) {
    int j = threadIdx.x;  // 0..63
    int k = blockIdx.x;   // 0..64; block 64 does b0
    if (k < 64) {
        float s = 0.f;
        for (int c = 0; c < 64; c++)
            s = fmaf(0.5f * (We[k * 128 + c] + We[k * 128 + 64 + c]), Wde[c * 64 + j], s);
        M[k * 64 + j] = s;
    } else {
        float s = bde[j];
        for (int c = 0; c < 64; c++) s = fmaf(be[c], Wde[c * 64 + j], s);
        b0[j] = s;
    }
}

// ---------------- encoder: one head per thread (h = blockIdx.y) ----------------
template <int K>
__global__ __launch_bounds__(256) void enc_gemm(const float* __restrict__ X, const float* __restrict__ W,
                                                const float* __restrict__ avs, const float* __restrict__ avd,
                                                float* __restrict__ xw, float* __restrict__ a_s,
                                                float* __restrict__ a_d, int Nn) {
    int n = blockIdx.x * 256 + threadIdx.x;
    int h = blockIdx.y;
    if (n >= Nn) return;
    const float* xr = X + (size_t)n * K;
    float acc[64];
#pragma unroll
    for (int j = 0; j < 64; j++) acc[j] = 0.f;
    for (int kc = 0; kc < K; kc += 16) {
        float xv[16];
#pragma unroll
        for (int i = 0; i < 16; i += 4) {
            float4 t = *(const float4*)(xr + kc + i);
            xv[i] = t.x; xv[i + 1] = t.y; xv[i + 2] = t.z; xv[i + 3] = t.w;
        }
#pragma unroll
        for (int k = 0; k < 16; k++) {
            const float* wr = W + (size_t)(kc + k) * 128 + h * 64;
#pragma unroll
            for (int j = 0; j < 64; j++) acc[j] = fmaf(xv[k], wr[j], acc[j]);
        }
    }
    float as = 0.f, ad = 0.f;
    const float* vs = avs + h * 64;
    const float* vd = avd + h * 64;
#pragma unroll
    for (int j = 0; j < 64; j++) { as = fmaf(acc[j], vs[j], as); ad = fmaf(acc[j], vd[j], ad); }
    float* xwr = xw + (size_t)n * 128 + h * 64;
#pragma unroll
    for (int j = 0; j < 64; j += 4) {
        float4 t = {acc[j], acc[j + 1], acc[j + 2], acc[j + 3]};
        *(float4*)(xwr + j) = t;
    }
    a_s[n * 2 + h] = as;
    a_d[n * 2 + h] = ad;
}

// ---------------- row-map: out[r,:] = A[r,:] @ M + b0   (A is [R,64], M is [64,OD]) ----------
// v4: col-per-lane compute (M[:,jc+lane] in 64 VGPRs, proven spill-free) + LDS-staged A.
//  - global->LDS staging is fully coalesced (tile = contiguous 32KB slab, float4/lane),
//    fixing v3's 16B-per-wave broadcast loads (9% HBM).
//  - LDS->reg row reads are wave-uniform ds_read_b128 broadcasts: conflict-free, latency
//    hidden by 8 independent FMA chains (2 rows x 4 partials).
//  - stores contiguous 256B/instr. ~4 blocks/CU (32KB LDS) overlap the stage barriers.
template <int OD>
__global__ __launch_bounds__(256) void rowmap_kernel(const float* __restrict__ A, const float* __restrict__ M,
                                                     const float* __restrict__ b0, float* __restrict__ out, int R) {
    __shared__ float sA[128 * 64];  // 32 KB
    int tid = threadIdx.x;
    int lane = tid & 63;
    int wave = tid >> 6;
    int jc = blockIdx.y * 64;
    int tile0 = blockIdx.x * 128;
    if (tile0 >= R) return;

    // per-lane M column cache (coalesced one-time load; stays in VGPRs after full unroll)
    float mc[64];
#pragma unroll
    for (int k = 0; k < 64; k++) mc[k] = M[(size_t)k * OD + jc + lane];
    float b0v = b0[jc + lane];

    int nrows = min(128, R - tile0);
    {   // stage A tile: nrows x 64 floats, coalesced float4 loads (8 per thread)
        const float4* Ag = (const float4*)(A + (size_t)tile0 * 64);
        float4* s4 = (float4*)sA;
        int maxq = nrows * 16;
#pragma unroll
        for (int i = 0; i < 8; i++) {
            int q = tid + i * 256;
            int qa = q < maxq ? q : 0;  // clamp partial tile to row 0 (valid global mem)
            s4[q] = Ag[qa];
        }
    }
    __syncthreads();

    int r0 = wave * 32;
    int rend = min(r0 + 32, nrows);
    for (int r = r0; r < rend; r += 2) {
        bool two = (r + 1 < rend);
        const float* a0 = sA + r * 64;
        const float* a1 = sA + (two ? (r + 1) : r) * 64;
        float p00 = b0v, p01 = 0.f, p02 = 0.f, p03 = 0.f;
        float p10 = b0v, p11 = 0.f, p12 = 0.f, p13 = 0.f;
#pragma unroll
        for (int kk = 0; kk < 16; kk++) {
            float4 v0 = *(const float4*)(a0 + kk * 4);  // wave-uniform LDS broadcast
            float4 v1 = *(const float4*)(a1 + kk * 4);
            p00 = fmaf(v0.x, mc[4 * kk + 0], p00);
            p01 = fmaf(v0.y, mc[4 * kk + 1], p01);
            p02 = fmaf(v0.z, mc[4 * kk + 2], p02);
            p03 = fmaf(v0.w, mc[4 * kk + 3], p03);
            p10 = fmaf(v1.x, mc[4 * kk + 0], p10);
            p11 = fmaf(v1.y, mc[4 * kk + 1], p11);
            p12 = fmaf(v1.z, mc[4 * kk + 2], p12);
            p13 = fmaf(v1.w, mc[4 * kk + 3], p13);
        }
        out[(size_t)(tile0 + r) * OD + jc + lane] = (p00 + p01) + (p02 + p03);
        if (two) out[(size_t)(tile0 + r + 1) * OD + jc + lane] = (p10 + p11) + (p12 + p13);
    }
}

// ---------------- fused message passing for BOTH convs; outputs head-mean hm ----------------
__global__ __launch_bounds__(128) void msg_fused(
    const float* __restrict__ xw_n, const float* __restrict__ a_sn, const float* __restrict__ a_dn,
    const float* __restrict__ xw_e, const float* __restrict__ a_se, const float* __restrict__ a_de,
    const int* __restrict__ rowptr, const int* __restrict__ ssrc,
    const float* __restrict__ bn, const float* __restrict__ be,
    float* __restrict__ hm_n, float* __restrict__ hm_e) {
    int n = blockIdx.x;
    int tid = threadIdx.x;
    int h = tid >> 6, c = tid & 63;
    __shared__ int s_src[MAXD];
    __shared__ float t_n[2][MAXD];
    __shared__ float t_e[2][MAXD];
    __shared__ float red[8];  // [conv*4 + {m0,m1,d0,d1}]
    __shared__ float hsh[2][128];

    int base = rowptr[n];
    int deg = rowptr[n + 1] - base;
    int degc = min(deg, MAXD);

    float adn0 = a_dn[n * 2 + 0], adn1 = a_dn[n * 2 + 1];
    float ade0 = a_de[n * 2 + 0], ade1 = a_de[n * 2 + 1];
    float2 asn_n = *(const float2*)(a_sn + (size_t)n * 2);
    float2 ase_n = *(const float2*)(a_se + (size_t)n * 2);
    float es_n0 = lrelu(asn_n.x + adn0), es_n1 = lrelu(asn_n.y + adn1);
    float es_e0 = lrelu(ase_n.x + ade0), es_e1 = lrelu(ase_n.y + ade1);

    // pass 1: cache src indices + leaky-relu logits (ONE gather over a_s)
    for (int i = tid; i < degc; i += 128) {
        int s = ssrc[base + i];
        s_src[i] = s;
        float2 an = *(const float2*)(a_sn + (size_t)s * 2);
        float2 ae = *(const float2*)(a_se + (size_t)s * 2);
        t_n[0][i] = lrelu(an.x + adn0);
        t_n[1][i] = lrelu(an.y + adn1);
        t_e[0][i] = lrelu(ae.x + ade0);
        t_e[1][i] = lrelu(ae.y + ade1);
    }
    __syncthreads();

    // reductions: wave 0 -> conv n, wave 1 -> conv e (both heads per wave)
    int w = tid >> 6;
    int lane = tid & 63;
    {
        const float(*tt)[MAXD] = w ? t_e : t_n;
        const float* asx = w ? a_se : a_sn;
        float ad0 = w ? ade0 : adn0, ad1 = w ? ade1 : adn1;
        float es0 = w ? es_e0 : es_n0, es1 = w ? es_e1 : es_n1;
        float m0 = es0, m1 = es1;
        for (int i = lane; i < degc; i += 64) { m0 = fmaxf(m0, tt[0][i]); m1 = fmaxf(m1, tt[1][i]); }
        for (int i = MAXD + lane; i < deg; i += 64) {
            int s = ssrc[base + i];
            float2 a = *(const float2*)(asx + (size_t)s * 2);
            m0 = fmaxf(m0, lrelu(a.x + ad0)); m1 = fmaxf(m1, lrelu(a.y + ad1));
        }
#pragma unroll
        for (int o = 1; o < 64; o <<= 1) { m0 = fmaxf(m0, __shfl_xor(m0, o)); m1 = fmaxf(m1, __shfl_xor(m1, o)); }
        // denominator: edge terms reduced across lanes; self term added ONCE after reduction
        float d0 = 0.f, d1 = 0.f;
        for (int i = lane; i < degc; i += 64) { d0 += __expf(tt[0][i] - m0); d1 += __expf(tt[1][i] - m1); }
        for (int i = MAXD + lane; i < deg; i += 64) {
            int s = ssrc[base + i];
            float2 a = *(const float2*)(asx + (size_t)s * 2);
            d0 += __expf(lrelu(a.x + ad0) - m0); d1 += __expf(lrelu(a.y + ad1) - m1);
        }
#pragma unroll
        for (int o = 1; o < 64; o <<= 1) { d0 += __shfl_xor(d0, o); d1 += __shfl_xor(d1, o); }
        d0 += __expf(es0 - m0);  // self-loop contribution, exactly once
        d1 += __expf(es1 - m1);
        if (lane == 0) { red[w * 4 + 0] = m0; red[w * 4 + 1] = m1; red[w * 4 + 2] = d0; red[w * 4 + 3] = d1; }
    }
    __syncthreads();

    // convert logits -> unnormalized weights in LDS (once)
    for (int i = tid; i < degc; i += 128) {
        t_n[0][i] = __expf(t_n[0][i] - red[0]);
        t_n[1][i] = __expf(t_n[1][i] - red[1]);
        t_e[0][i] = __expf(t_e[0][i] - red[4]);
        t_e[1][i] = __expf(t_e[1][i] - red[5]);
    }
    __syncthreads();

    float mn = red[h], dn_ = red[2 + h];
    float me = red[4 + h], de_ = red[6 + h];
    float accn = __expf((h ? es_n1 : es_n0) - mn) * xw_n[(size_t)n * 128 + h * 64 + c];
    float acce = __expf((h ? es_e1 : es_e0) - me) * xw_e[(size_t)n * 128 + h * 64 + c];
    for (int i = 0; i < degc; i++) {
        int s = s_src[i];
        float wn_ = t_n[h][i];
        float we_ = t_e[h][i];
        accn = fmaf(wn_, xw_n[(size_t)s * 128 + h * 64 + c], accn);
        acce = fmaf(we_, xw_e[(size_t)s * 128 + h * 64 + c], acce);
    }
    for (int i = MAXD; i < deg; i++) {
        int s = ssrc[base + i];
        float2 an = *(const float2*)(a_sn + (size_t)s * 2);
        float2 ae = *(const float2*)(a_se + (size_t)s * 2);
        float tn_ = lrelu(h ? (an.y + adn1) : (an.x + adn0));
        float te_ = lrelu(h ? (ae.y + ade1) : (ae.x + ade0));
        accn = fmaf(__expf(tn_ - mn), xw_n[(size_t)s * 128 + h * 64 + c], accn);
        acce = fmaf(__expf(te_ - me), xw_e[(size_t)s * 128 + h * 64 + c], acce);
    }
    hsh[0][tid] = accn / dn_;
    hsh[1][tid] = acce / de_;
    __syncthreads();
    if (tid < 64) {
        hm_n[(size_t)n * 64 + tid] = fmaf(0.5f, hsh[0][tid] + hsh[0][64 + tid], bn[tid]);
        hm_e[(size_t)n * 64 + tid] = fmaf(0.5f, hsh[1][tid] + hsh[1][64 + tid], be[tid]);
    }
}

extern "C" void kernel_launch(void* const* d_in, const int* in_sizes, int n_in,
                              void* d_out, int out_size, void* d_ws, size_t ws_size,
                              hipStream_t stream) {
    const float* x   = (const float*)d_in[0];
    const float* xe  = (const float*)d_in[1];
    const int*   ei  = (const int*)d_in[2];
    const float* Wn  = (const float*)d_in[3];
    const float* asn = (const float*)d_in[4];
    const float* adn = (const float*)d_in[5];
    const float* bn  = (const float*)d_in[6];
    const float* We  = (const float*)d_in[7];
    const float* ase = (const float*)d_in[8];
    const float* ade = (const float*)d_in[9];
    const float* be  = (const float*)d_in[10];
    const float* Wdx = (const float*)d_in[11];
    const float* bdx = (const float*)d_in[12];
    const float* Wde = (const float*)d_in[13];
    const float* bde = (const float*)d_in[14];

    const int N  = in_sizes[0] / 128;  // 50000
    const int NE = in_sizes[1] / 64;   // 800000
    const int E  = in_sizes[2] / 2;    // 800000
    const int* src = ei;
    const int* dst = ei + E;

    char* wsb = (char*)d_ws;
    size_t off = 0;
    auto alloc = [&](size_t bytes) -> void* {
        void* p = wsb + off;
        off += (bytes + 255) & ~(size_t)255;
        return p;
    };
    float* xw_n = (float*)alloc((size_t)N * 128 * 4);
    float* a_sn = (float*)alloc((size_t)N * 2 * 4);
    float* a_dn = (float*)alloc((size_t)N * 2 * 4);
    float* xw_e = (float*)alloc((size_t)N * 128 * 4);
    float* a_se = (float*)alloc((size_t)N * 2 * 4);
    float* a_de = (float*)alloc((size_t)N * 2 * 4);
    float* hm_n = (float*)alloc((size_t)N * 64 * 4);
    float* hm_e = (float*)alloc((size_t)N * 64 * 4);
    float* Mt   = (float*)alloc((size_t)64 * 64 * 4);
    float* b0t  = (float*)alloc((size_t)64 * 4);
    int* cnt    = (int*)alloc((size_t)(N + 1) * 4);
    int* rowptr = (int*)alloc((size_t)(N + 1) * 4);
    int* cursor = (int*)alloc((size_t)(N + 1) * 4);
    int* ssrc   = (int*)alloc((size_t)E * 4);

    float* x_rec = (float*)d_out;
    float* e_rec = (float*)d_out + (size_t)N * 128;

    // CSR build (shared by both convs)
    hipMemsetAsync(cnt, 0, (size_t)N * 4, stream);
    count_kernel<<<(E + 255) / 256, 256, 0, stream>>>(dst, cnt, E);
    scan_kernel<<<1, 1024, 0, stream>>>(cnt, rowptr, N);
    hipMemcpyAsync(cursor, rowptr, (size_t)N * 4, hipMemcpyDeviceToDevice, stream);
    scatter_kernel<<<(E + 255) / 256, 256, 0, stream>>>(src, dst, cursor, ssrc, E);

    // Fold tail affine map
    fold_kernel<<<65, 64, 0, stream>>>(We, Wde, be, bde, Mt, b0t);

    // Encoders (one head per thread)
    enc_gemm<128><<<dim3((N + 255) / 256, 2), 256, 0, stream>>>(x, Wn, asn, adn, xw_n, a_sn, a_dn, N);
    enc_gemm<64><<<dim3((N + 255) / 256, 2), 256, 0, stream>>>(xe, We, ase, ade, xw_e, a_se, a_de, N);

    // Tail: 750k self-loop-only rows, folded to a single affine map (LDS-staged col-per-lane)
    {
        int R = NE - N;
        rowmap_kernel<64><<<dim3((R + 127) / 128, 1), 256, 0, stream>>>(
            xe + (size_t)N * 64, Mt, b0t, e_rec + (size_t)N * 64, R);
    }

    // Fused message passing for both convs -> head-mean hidden states
    msg_fused<<<N, 128, 0, stream>>>(xw_n, a_sn, a_dn, xw_e, a_se, a_de, rowptr, ssrc, bn, be, hm_n, hm_e);

    // Decoders (LDS-staged col-per-lane; OD=128 splits column halves across gridDim.y)
    rowmap_kernel<128><<<dim3((N + 127) / 128, 2), 256, 0, stream>>>(hm_n, Wdx, bdx, x_rec, N);
    rowmap_kernel<64><<<dim3((N + 127) / 128, 1), 256, 0, stream>>>(hm_e, Wde, bde, e_rec, N);
}

// Round 6
// 846.886 us; speedup vs baseline: 3.3353x; 1.3572x over previous
//
#include <hip/hip_runtime.h>
#include <hip/hip_bf16.h>

// H=2, C=64, IN=128, EIN=64, N=50000, E=800000
constexpr int MAXD = 512;

__device__ __forceinline__ float lrelu(float v) { return v >= 0.f ? v : 0.2f * v; }

// ---------------- CSR build ----------------
__global__ void count_kernel(const int* __restrict__ dst, int* __restrict__ cnt, int E) {
    int e = blockIdx.x * blockDim.x + threadIdx.x;
    if (e < E) atomicAdd(&cnt[dst[e]], 1);
}

__global__ __launch_bounds__(1024) void scan_kernel(const int* __restrict__ cnt, int* __restrict__ rowptr, int n) {
    __shared__ int part[1024];
    int t = threadIdx.x;
    int CH = (n + 1023) / 1024;
    int base = t * CH;
    int local = 0;
    for (int i = 0; i < CH; i++) { int idx = base + i; if (idx < n) local += cnt[idx]; }
    part[t] = local;
    __syncthreads();
    for (int o = 1; o < 1024; o <<= 1) {
        int v = (t >= o) ? part[t - o] : 0;
        __syncthreads();
        part[t] += v;
        __syncthreads();
    }
    int run = part[t] - local;  // exclusive prefix
    for (int i = 0; i < CH; i++) {
        int idx = base + i;
        if (idx < n) { rowptr[idx] = run; run += cnt[idx]; }
    }
    if (t == 1023) rowptr[n] = run;
}

__global__ void scatter_kernel(const int* __restrict__ src, const int* __restrict__ dst,
                               int* __restrict__ cursor, int* __restrict__ ssrc, int E) {
    int e = blockIdx.x * blockDim.x + threadIdx.x;
    if (e < E) {
        int pos = atomicAdd(&cursor[dst[e]], 1);
        ssrc[pos] = src[e];
    }
}

// ---------------- fold: M = We_fold @ Wde, b0 = be@Wde + bde ----------------
__global__ void fold_kernel(const float* __restrict__ We, const float* __restrict__ Wde,
                            const float* __restrict__ be, const float* __restrict__ bde,
                            float* __restrict__ M, float* __restrict__ b0) {
    int j = threadIdx.x;  // 0..63
    int k = blockIdx.x;   // 0..64; block 64 does b0
    if (k < 64) {
        float s = 0.f;
        for (int c = 0; c < 64; c++)
            s = fmaf(0.5f * (We[k * 128 + c] + We[k * 128 + 64 + c]), Wde[c * 64 + j], s);
        M[k * 64 + j] = s;
    } else {
        float s = bde[j];
        for (int c = 0; c < 64; c++) s = fmaf(be[c], Wde[c * 64 + j], s);
        b0[j] = s;
    }
}

// ---------------- encoder: one head per thread (h = blockIdx.y) ----------------
template <int K>
__global__ __launch_bounds__(256) void enc_gemm(const float* __restrict__ X, const float* __restrict__ W,
                                                const float* __restrict__ avs, const float* __restrict__ avd,
                                                float* __restrict__ xw, float* __restrict__ a_s,
                                                float* __restrict__ a_d, int Nn) {
    int n = blockIdx.x * 256 + threadIdx.x;
    int h = blockIdx.y;
    if (n >= Nn) return;
    const float* xr = X + (size_t)n * K;
    float acc[64];
#pragma unroll
    for (int j = 0; j < 64; j++) acc[j] = 0.f;
    for (int kc = 0; kc < K; kc += 16) {
        float xv[16];
#pragma unroll
        for (int i = 0; i < 16; i += 4) {
            float4 t = *(const float4*)(xr + kc + i);
            xv[i] = t.x; xv[i + 1] = t.y; xv[i + 2] = t.z; xv[i + 3] = t.w;
        }
#pragma unroll
        for (int k = 0; k < 16; k++) {
            const float* wr = W + (size_t)(kc + k) * 128 + h * 64;
#pragma unroll
            for (int j = 0; j < 64; j++) acc[j] = fmaf(xv[k], wr[j], acc[j]);
        }
    }
    float as = 0.f, ad = 0.f;
    const float* vs = avs + h * 64;
    const float* vd = avd + h * 64;
#pragma unroll
    for (int j = 0; j < 64; j++) { as = fmaf(acc[j], vs[j], as); ad = fmaf(acc[j], vd[j], ad); }
    float* xwr = xw + (size_t)n * 128 + h * 64;
#pragma unroll
    for (int j = 0; j < 64; j += 4) {
        float4 t = {acc[j], acc[j + 1], acc[j + 2], acc[j + 3]};
        *(float4*)(xwr + j) = t;
    }
    a_s[n * 2 + h] = as;
    a_d[n * 2 + h] = ad;
}

// ---------------- row-map: out[r,:] = A[r,:] @ M + b0   (A is [R,64], M is [64,OD]) ----------
// v5: register-tiled GEMM. Block=256 threads, tile=128 rows x 64 cols; thread (tr=tid&15,
// tj=tid>>4) owns an 8x4 output tile (rows tr+16i, cols 4tj..4tj+3). BOTH fragments are
// lane-varying LDS reads (v3/v4 lesson: wave-uniform broadcast reads deliver 16B/instr and
// bottleneck a pipe). Per k-quad: 8 A-frag ds_read_b128 (XOR-swizzled sA: rows r,r+8 alias
// -> 2-way conflict = free) + 4 M-frag reads (conflict-free) feed 128 FMAs -> VALU-bound.
// A-tile staged coalesced (1KB/instr); M block (16KB) staged per block. k-order preserved.
template <int OD>
__global__ __launch_bounds__(256) void rowmap_kernel(const float* __restrict__ A, const float* __restrict__ M,
                                                     const float* __restrict__ b0, float* __restrict__ out, int R) {
    __shared__ float4 sA4[128 * 16];  // 32 KB, quad index XOR-swizzled by (row&15)
    __shared__ float4 sM4[64 * 16];   // 16 KB
    int tid = threadIdx.x;
    int tr = tid & 15;   // row group: rows tr + 16*i
    int tj = tid >> 4;   // col group: cols 4*tj .. 4*tj+3
    int jc = blockIdx.y * 64;
    int tile0 = blockIdx.x * 128;
    if (tile0 >= R) return;
    int nrows = min(128, R - tile0);

    // stage M block [64 x 64] (cols jc..jc+63), linear layout
#pragma unroll
    for (int it = 0; it < 4; it++) {
        int f = tid + it * 256;  // f = k*16 + jq
        int k = f >> 4, jq = f & 15;
        sM4[f] = *(const float4*)(M + (size_t)k * OD + jc + 4 * jq);
    }
    // stage A tile [nrows x 64], coalesced global float4, swizzled LDS store
    {
        const float4* Ag = (const float4*)(A + (size_t)tile0 * 64);
#pragma unroll
        for (int it = 0; it < 8; it++) {
            int e = tid + it * 256;
            int r = e >> 4, q = e & 15;
            int srcq = (r < nrows) ? e : q;  // clamp OOB rows of partial tile to row 0
            sA4[(r << 4) | (q ^ (r & 15))] = Ag[srcq];
        }
    }
    __syncthreads();

    float4 b0v = *(const float4*)(b0 + jc + 4 * tj);
    float acc[8][4];
#pragma unroll
    for (int i = 0; i < 8; i++) { acc[i][0] = b0v.x; acc[i][1] = b0v.y; acc[i][2] = b0v.z; acc[i][3] = b0v.w; }

    for (int kq = 0; kq < 16; kq++) {
        float4 mf0 = sM4[(4 * kq + 0) * 16 + tj];
        float4 mf1 = sM4[(4 * kq + 1) * 16 + tj];
        float4 mf2 = sM4[(4 * kq + 2) * 16 + tj];
        float4 mf3 = sM4[(4 * kq + 3) * 16 + tj];
#pragma unroll
        for (int i = 0; i < 8; i++) {
            int row = tr + 16 * i;  // row & 15 == tr
            float4 af = sA4[(row << 4) | (kq ^ tr)];
            acc[i][0] = fmaf(af.x, mf0.x, acc[i][0]);
            acc[i][0] = fmaf(af.y, mf1.x, acc[i][0]);
            acc[i][0] = fmaf(af.z, mf2.x, acc[i][0]);
            acc[i][0] = fmaf(af.w, mf3.x, acc[i][0]);
            acc[i][1] = fmaf(af.x, mf0.y, acc[i][1]);
            acc[i][1] = fmaf(af.y, mf1.y, acc[i][1]);
            acc[i][1] = fmaf(af.z, mf2.y, acc[i][1]);
            acc[i][1] = fmaf(af.w, mf3.y, acc[i][1]);
            acc[i][2] = fmaf(af.x, mf0.z, acc[i][2]);
            acc[i][2] = fmaf(af.y, mf1.z, acc[i][2]);
            acc[i][2] = fmaf(af.z, mf2.z, acc[i][2]);
            acc[i][2] = fmaf(af.w, mf3.z, acc[i][2]);
            acc[i][3] = fmaf(af.x, mf0.w, acc[i][3]);
            acc[i][3] = fmaf(af.y, mf1.w, acc[i][3]);
            acc[i][3] = fmaf(af.z, mf2.w, acc[i][3]);
            acc[i][3] = fmaf(af.w, mf3.w, acc[i][3]);
        }
    }

#pragma unroll
    for (int i = 0; i < 8; i++) {
        int row = tr + 16 * i;
        if (row < nrows) {
            float4 t = {acc[i][0], acc[i][1], acc[i][2], acc[i][3]};
            *(float4*)(out + (size_t)(tile0 + row) * OD + jc + 4 * tj) = t;
        }
    }
}

// ---------------- fused message passing for BOTH convs; outputs head-mean hm ----------------
__global__ __launch_bounds__(128) void msg_fused(
    const float* __restrict__ xw_n, const float* __restrict__ a_sn, const float* __restrict__ a_dn,
    const float* __restrict__ xw_e, const float* __restrict__ a_se, const float* __restrict__ a_de,
    const int* __restrict__ rowptr, const int* __restrict__ ssrc,
    const float* __restrict__ bn, const float* __restrict__ be,
    float* __restrict__ hm_n, float* __restrict__ hm_e) {
    int n = blockIdx.x;
    int tid = threadIdx.x;
    int h = tid >> 6, c = tid & 63;
    __shared__ int s_src[MAXD];
    __shared__ float t_n[2][MAXD];
    __shared__ float t_e[2][MAXD];
    __shared__ float red[8];  // [conv*4 + {m0,m1,d0,d1}]
    __shared__ float hsh[2][128];

    int base = rowptr[n];
    int deg = rowptr[n + 1] - base;
    int degc = min(deg, MAXD);

    float adn0 = a_dn[n * 2 + 0], adn1 = a_dn[n * 2 + 1];
    float ade0 = a_de[n * 2 + 0], ade1 = a_de[n * 2 + 1];
    float2 asn_n = *(const float2*)(a_sn + (size_t)n * 2);
    float2 ase_n = *(const float2*)(a_se + (size_t)n * 2);
    float es_n0 = lrelu(asn_n.x + adn0), es_n1 = lrelu(asn_n.y + adn1);
    float es_e0 = lrelu(ase_n.x + ade0), es_e1 = lrelu(ase_n.y + ade1);

    // pass 1: cache src indices + leaky-relu logits (ONE gather over a_s)
    for (int i = tid; i < degc; i += 128) {
        int s = ssrc[base + i];
        s_src[i] = s;
        float2 an = *(const float2*)(a_sn + (size_t)s * 2);
        float2 ae = *(const float2*)(a_se + (size_t)s * 2);
        t_n[0][i] = lrelu(an.x + adn0);
        t_n[1][i] = lrelu(an.y + adn1);
        t_e[0][i] = lrelu(ae.x + ade0);
        t_e[1][i] = lrelu(ae.y + ade1);
    }
    __syncthreads();

    // reductions: wave 0 -> conv n, wave 1 -> conv e (both heads per wave)
    int w = tid >> 6;
    int lane = tid & 63;
    {
        const float(*tt)[MAXD] = w ? t_e : t_n;
        const float* asx = w ? a_se : a_sn;
        float ad0 = w ? ade0 : adn0, ad1 = w ? ade1 : adn1;
        float es0 = w ? es_e0 : es_n0, es1 = w ? es_e1 : es_n1;
        float m0 = es0, m1 = es1;
        for (int i = lane; i < degc; i += 64) { m0 = fmaxf(m0, tt[0][i]); m1 = fmaxf(m1, tt[1][i]); }
        for (int i = MAXD + lane; i < deg; i += 64) {
            int s = ssrc[base + i];
            float2 a = *(const float2*)(asx + (size_t)s * 2);
            m0 = fmaxf(m0, lrelu(a.x + ad0)); m1 = fmaxf(m1, lrelu(a.y + ad1));
        }
#pragma unroll
        for (int o = 1; o < 64; o <<= 1) { m0 = fmaxf(m0, __shfl_xor(m0, o)); m1 = fmaxf(m1, __shfl_xor(m1, o)); }
        // denominator: edge terms reduced across lanes; self term added ONCE after reduction
        float d0 = 0.f, d1 = 0.f;
        for (int i = lane; i < degc; i += 64) { d0 += __expf(tt[0][i] - m0); d1 += __expf(tt[1][i] - m1); }
        for (int i = MAXD + lane; i < deg; i += 64) {
            int s = ssrc[base + i];
            float2 a = *(const float2*)(asx + (size_t)s * 2);
            d0 += __expf(lrelu(a.x + ad0) - m0); d1 += __expf(lrelu(a.y + ad1) - m1);
        }
#pragma unroll
        for (int o = 1; o < 64; o <<= 1) { d0 += __shfl_xor(d0, o); d1 += __shfl_xor(d1, o); }
        d0 += __expf(es0 - m0);  // self-loop contribution, exactly once
        d1 += __expf(es1 - m1);
        if (lane == 0) { red[w * 4 + 0] = m0; red[w * 4 + 1] = m1; red[w * 4 + 2] = d0; red[w * 4 + 3] = d1; }
    }
    __syncthreads();

    // convert logits -> unnormalized weights in LDS (once)
    for (int i = tid; i < degc; i += 128) {
        t_n[0][i] = __expf(t_n[0][i] - red[0]);
        t_n[1][i] = __expf(t_n[1][i] - red[1]);
        t_e[0][i] = __expf(t_e[0][i] - red[4]);
        t_e[1][i] = __expf(t_e[1][i] - red[5]);
    }
    __syncthreads();

    float mn = red[h], dn_ = red[2 + h];
    float me = red[4 + h], de_ = red[6 + h];
    float accn = __expf((h ? es_n1 : es_n0) - mn) * xw_n[(size_t)n * 128 + h * 64 + c];
    float acce = __expf((h ? es_e1 : es_e0) - me) * xw_e[(size_t)n * 128 + h * 64 + c];
    for (int i = 0; i < degc; i++) {
        int s = s_src[i];
        float wn_ = t_n[h][i];
        float we_ = t_e[h][i];
        accn = fmaf(wn_, xw_n[(size_t)s * 128 + h * 64 + c], accn);
        acce = fmaf(we_, xw_e[(size_t)s * 128 + h * 64 + c], acce);
    }
    for (int i = MAXD; i < deg; i++) {
        int s = ssrc[base + i];
        float2 an = *(const float2*)(a_sn + (size_t)s * 2);
        float2 ae = *(const float2*)(a_se + (size_t)s * 2);
        float tn_ = lrelu(h ? (an.y + adn1) : (an.x + adn0));
        float te_ = lrelu(h ? (ae.y + ade1) : (ae.x + ade0));
        accn = fmaf(__expf(tn_ - mn), xw_n[(size_t)s * 128 + h * 64 + c], accn);
        acce = fmaf(__expf(te_ - me), xw_e[(size_t)s * 128 + h * 64 + c], acce);
    }
    hsh[0][tid] = accn / dn_;
    hsh[1][tid] = acce / de_;
    __syncthreads();
    if (tid < 64) {
        hm_n[(size_t)n * 64 + tid] = fmaf(0.5f, hsh[0][tid] + hsh[0][64 + tid], bn[tid]);
        hm_e[(size_t)n * 64 + tid] = fmaf(0.5f, hsh[1][tid] + hsh[1][64 + tid], be[tid]);
    }
}

extern "C" void kernel_launch(void* const* d_in, const int* in_sizes, int n_in,
                              void* d_out, int out_size, void* d_ws, size_t ws_size,
                              hipStream_t stream) {
    const float* x   = (const float*)d_in[0];
    const float* xe  = (const float*)d_in[1];
    const int*   ei  = (const int*)d_in[2];
    const float* Wn  = (const float*)d_in[3];
    const float* asn = (const float*)d_in[4];
    const float* adn = (const float*)d_in[5];
    const float* bn  = (const float*)d_in[6];
    const float* We  = (const float*)d_in[7];
    const float* ase = (const float*)d_in[8];
    const float* ade = (const float*)d_in[9];
    const float* be  = (const float*)d_in[10];
    const float* Wdx = (const float*)d_in[11];
    const float* bdx = (const float*)d_in[12];
    const float* Wde = (const float*)d_in[13];
    const float* bde = (const float*)d_in[14];

    const int N  = in_sizes[0] / 128;  // 50000
    const int NE = in_sizes[1] / 64;   // 800000
    const int E  = in_sizes[2] / 2;    // 800000
    const int* src = ei;
    const int* dst = ei + E;

    char* wsb = (char*)d_ws;
    size_t off = 0;
    auto alloc = [&](size_t bytes) -> void* {
        void* p = wsb + off;
        off += (bytes + 255) & ~(size_t)255;
        return p;
    };
    float* xw_n = (float*)alloc((size_t)N * 128 * 4);
    float* a_sn = (float*)alloc((size_t)N * 2 * 4);
    float* a_dn = (float*)alloc((size_t)N * 2 * 4);
    float* xw_e = (float*)alloc((size_t)N * 128 * 4);
    float* a_se = (float*)alloc((size_t)N * 2 * 4);
    float* a_de = (float*)alloc((size_t)N * 2 * 4);
    float* hm_n = (float*)alloc((size_t)N * 64 * 4);
    float* hm_e = (float*)alloc((size_t)N * 64 * 4);
    float* Mt   = (float*)alloc((size_t)64 * 64 * 4);
    float* b0t  = (float*)alloc((size_t)64 * 4);
    int* cnt    = (int*)alloc((size_t)(N + 1) * 4);
    int* rowptr = (int*)alloc((size_t)(N + 1) * 4);
    int* cursor = (int*)alloc((size_t)(N + 1) * 4);
    int* ssrc   = (int*)alloc((size_t)E * 4);

    float* x_rec = (float*)d_out;
    float* e_rec = (float*)d_out + (size_t)N * 128;

    // CSR build (shared by both convs)
    hipMemsetAsync(cnt, 0, (size_t)N * 4, stream);
    count_kernel<<<(E + 255) / 256, 256, 0, stream>>>(dst, cnt, E);
    scan_kernel<<<1, 1024, 0, stream>>>(cnt, rowptr, N);
    hipMemcpyAsync(cursor, rowptr, (size_t)N * 4, hipMemcpyDeviceToDevice, stream);
    scatter_kernel<<<(E + 255) / 256, 256, 0, stream>>>(src, dst, cursor, ssrc, E);

    // Fold tail affine map
    fold_kernel<<<65, 64, 0, stream>>>(We, Wde, be, bde, Mt, b0t);

    // Encoders (one head per thread)
    enc_gemm<128><<<dim3((N + 255) / 256, 2), 256, 0, stream>>>(x, Wn, asn, adn, xw_n, a_sn, a_dn, N);
    enc_gemm<64><<<dim3((N + 255) / 256, 2), 256, 0, stream>>>(xe, We, ase, ade, xw_e, a_se, a_de, N);

    // Tail: 750k self-loop-only rows, folded to a single affine map (register-tiled GEMM)
    {
        int R = NE - N;
        rowmap_kernel<64><<<dim3((R + 127) / 128, 1), 256, 0, stream>>>(
            xe + (size_t)N * 64, Mt, b0t, e_rec + (size_t)N * 64, R);
    }

    // Fused message passing for both convs -> head-mean hidden states
    msg_fused<<<N, 128, 0, stream>>>(xw_n, a_sn, a_dn, xw_e, a_se, a_de, rowptr, ssrc, bn, be, hm_n, hm_e);

    // Decoders (register-tiled GEMM; OD=128 splits column halves across gridDim.y)
    rowmap_kernel<128><<<dim3((N + 127) / 128, 2), 256, 0, stream>>>(hm_n, Wdx, bdx, x_rec, N);
    rowmap_kernel<64><<<dim3((N + 127) / 128, 1), 256, 0, stream>>>(hm_e, Wde, bde, e_rec, N);
}

// Round 7
// 791.114 us; speedup vs baseline: 3.5704x; 1.0705x over previous
//
#include <hip/hip_runtime.h>
#include <hip/hip_bf16.h>

// H=2, C=64, IN=128, EIN=64, N=50000, E=800000
constexpr int MAXD = 512;

__device__ __forceinline__ float lrelu(float v) { return v >= 0.f ? v : 0.2f * v; }

// ---------------- CSR build ----------------
__global__ void count_kernel(const int* __restrict__ dst, int* __restrict__ cnt, int E) {
    int e = blockIdx.x * blockDim.x + threadIdx.x;
    if (e < E) atomicAdd(&cnt[dst[e]], 1);
}

__global__ __launch_bounds__(1024) void scan_kernel(const int* __restrict__ cnt, int* __restrict__ rowptr, int n) {
    __shared__ int part[1024];
    int t = threadIdx.x;
    int CH = (n + 1023) / 1024;
    int base = t * CH;
    int local = 0;
    for (int i = 0; i < CH; i++) { int idx = base + i; if (idx < n) local += cnt[idx]; }
    part[t] = local;
    __syncthreads();
    for (int o = 1; o < 1024; o <<= 1) {
        int v = (t >= o) ? part[t - o] : 0;
        __syncthreads();
        part[t] += v;
        __syncthreads();
    }
    int run = part[t] - local;  // exclusive prefix
    for (int i = 0; i < CH; i++) {
        int idx = base + i;
        if (idx < n) { rowptr[idx] = run; run += cnt[idx]; }
    }
    if (t == 1023) rowptr[n] = run;
}

__global__ void scatter_kernel(const int* __restrict__ src, const int* __restrict__ dst,
                               int* __restrict__ cursor, int* __restrict__ ssrc, int E) {
    int e = blockIdx.x * blockDim.x + threadIdx.x;
    if (e < E) {
        int pos = atomicAdd(&cursor[dst[e]], 1);
        ssrc[pos] = src[e];
    }
}

// ---------------- fold: M = We_fold @ Wde, b0 = be@Wde + bde ----------------
__global__ void fold_kernel(const float* __restrict__ We, const float* __restrict__ Wde,
                            const float* __restrict__ be, const float* __restrict__ bde,
                            float* __restrict__ M, float* __restrict__ b0) {
    int j = threadIdx.x;  // 0..63
    int k = blockIdx.x;   // 0..64; block 64 does b0
    if (k < 64) {
        float s = 0.f;
        for (int c = 0; c < 64; c++)
            s = fmaf(0.5f * (We[k * 128 + c] + We[k * 128 + 64 + c]), Wde[c * 64 + j], s);
        M[k * 64 + j] = s;
    } else {
        float s = bde[j];
        for (int c = 0; c < 64; c++) s = fmaf(be[c], Wde[c * 64 + j], s);
        b0[j] = s;
    }
}

// ---------------- encoder v2: register-tiled GEMM (v5 structure) + fused a_s/a_d ----------
// Old enc_gemm was thread-per-row: wave's X loads touched 64 cache lines/instr (the v1
// rowmap pathology). Here X is staged coalesced to LDS and both fragments are lane-varying.
// Tile 128 rows x 64 cols (one head per blockIdx.y); K staged in 64-wide slabs.
// Epilogue computes a_s/a_d = xw . a_src/a_dst via per-thread 4-col partials + padded-LDS
// 16-way reduction over tj (stride 17 -> conflict-free), reusing sA4 after a barrier.
template <int K>
__global__ __launch_bounds__(256) void enc_tiled(const float* __restrict__ X, const float* __restrict__ W,
                                                 const float* __restrict__ avs, const float* __restrict__ avd,
                                                 float* __restrict__ xw, float* __restrict__ a_s,
                                                 float* __restrict__ a_d, int Nn) {
    __shared__ float4 sA4[128 * 16];  // 32 KB: 128 rows x 16 quads of current k-slab (swizzled)
    __shared__ float4 sM4[64 * 16];   // 16 KB: 64 k x 16 col-quads
    int tid = threadIdx.x;
    int tr = tid & 15;   // rows tr + 16*i
    int tj = tid >> 4;   // cols 4*tj .. 4*tj+3
    int h = blockIdx.y;
    int jc = h * 64;
    int tile0 = blockIdx.x * 128;
    if (tile0 >= Nn) return;
    int nrows = min(128, Nn - tile0);

    float acc[8][4];
#pragma unroll
    for (int i = 0; i < 8; i++) { acc[i][0] = 0.f; acc[i][1] = 0.f; acc[i][2] = 0.f; acc[i][3] = 0.f; }

    for (int kc = 0; kc < K; kc += 64) {
        if (kc) __syncthreads();  // previous slab fully consumed before restage
        // stage W[kc+k][jc + 4*jq] (row stride 128 = H*C)
#pragma unroll
        for (int it = 0; it < 4; it++) {
            int f = tid + it * 256;  // f = k*16 + jq
            int k = f >> 4, jq = f & 15;
            sM4[f] = *(const float4*)(W + (size_t)(kc + k) * 128 + jc + 4 * jq);
        }
        // stage X[tile0+r][kc + 4*q], coalesced, swizzled LDS store
#pragma unroll
        for (int it = 0; it < 8; it++) {
            int e = tid + it * 256;
            int r = e >> 4, q = e & 15;
            int rs = (r < nrows) ? r : 0;  // clamp OOB rows of partial tile to tile row 0
            sA4[(r << 4) | (q ^ (r & 15))] = *(const float4*)(X + (size_t)(tile0 + rs) * K + kc + 4 * q);
        }
        __syncthreads();
        for (int kq = 0; kq < 16; kq++) {
            float4 mf0 = sM4[(4 * kq + 0) * 16 + tj];
            float4 mf1 = sM4[(4 * kq + 1) * 16 + tj];
            float4 mf2 = sM4[(4 * kq + 2) * 16 + tj];
            float4 mf3 = sM4[(4 * kq + 3) * 16 + tj];
#pragma unroll
            for (int i = 0; i < 8; i++) {
                int row = tr + 16 * i;  // row & 15 == tr
                float4 af = sA4[(row << 4) | (kq ^ tr)];
                acc[i][0] = fmaf(af.x, mf0.x, acc[i][0]);
                acc[i][0] = fmaf(af.y, mf1.x, acc[i][0]);
                acc[i][0] = fmaf(af.z, mf2.x, acc[i][0]);
                acc[i][0] = fmaf(af.w, mf3.x, acc[i][0]);
                acc[i][1] = fmaf(af.x, mf0.y, acc[i][1]);
                acc[i][1] = fmaf(af.y, mf1.y, acc[i][1]);
                acc[i][1] = fmaf(af.z, mf2.y, acc[i][1]);
                acc[i][1] = fmaf(af.w, mf3.y, acc[i][1]);
                acc[i][2] = fmaf(af.x, mf0.z, acc[i][2]);
                acc[i][2] = fmaf(af.y, mf1.z, acc[i][2]);
                acc[i][2] = fmaf(af.z, mf2.z, acc[i][2]);
                acc[i][2] = fmaf(af.w, mf3.z, acc[i][2]);
                acc[i][3] = fmaf(af.x, mf0.w, acc[i][3]);
                acc[i][3] = fmaf(af.y, mf1.w, acc[i][3]);
                acc[i][3] = fmaf(af.z, mf2.w, acc[i][3]);
                acc[i][3] = fmaf(af.w, mf3.w, acc[i][3]);
            }
        }
    }

    // write xw tile
#pragma unroll
    for (int i = 0; i < 8; i++) {
        int row = tr + 16 * i;
        if (row < nrows) {
            float4 t = {acc[i][0], acc[i][1], acc[i][2], acc[i][3]};
            *(float4*)(xw + (size_t)(tile0 + row) * 128 + jc + 4 * tj) = t;
        }
    }

    // fused a_s/a_d: per-thread 4-col partials, then 16-way tj-reduction in padded LDS
    float4 vs = *(const float4*)(avs + jc + 4 * tj);
    float4 vd = *(const float4*)(avd + jc + 4 * tj);
    __syncthreads();  // all threads done reading sA4/sM4
    float* red = (float*)sA4;  // reuse: [128][17] s-partials, then +4096: [128][17] d-partials
#pragma unroll
    for (int i = 0; i < 8; i++) {
        int row = tr + 16 * i;
        float ps = acc[i][0] * vs.x + acc[i][1] * vs.y + acc[i][2] * vs.z + acc[i][3] * vs.w;
        float pd = acc[i][0] * vd.x + acc[i][1] * vd.y + acc[i][2] * vd.z + acc[i][3] * vd.w;
        red[row * 17 + tj] = ps;
        red[4096 + row * 17 + tj] = pd;
    }
    __syncthreads();
    if (tid < 128 && tid < nrows) {
        float ss = 0.f, sd = 0.f;
#pragma unroll
        for (int t = 0; t < 16; t++) { ss += red[tid * 17 + t]; sd += red[4096 + tid * 17 + t]; }
        a_s[(size_t)(tile0 + tid) * 2 + h] = ss;
        a_d[(size_t)(tile0 + tid) * 2 + h] = sd;
    }
}

// ---------------- row-map: out[r,:] = A[r,:] @ M + b0   (A is [R,64], M is [64,OD]) ----------
// v5: register-tiled GEMM. Block=256 threads, tile=128 rows x 64 cols; thread (tr=tid&15,
// tj=tid>>4) owns an 8x4 output tile (rows tr+16i, cols 4tj..4tj+3). BOTH fragments are
// lane-varying LDS reads (v3/v4 lesson: wave-uniform broadcast reads deliver 16B/instr and
// bottleneck a pipe). Per k-quad: 8 A-frag ds_read_b128 (XOR-swizzled sA: 2-way = free) +
// 4 M-frag reads (conflict-free) feed 128 FMAs -> VALU-bound. k-order preserved.
template <int OD>
__global__ __launch_bounds__(256) void rowmap_kernel(const float* __restrict__ A, const float* __restrict__ M,
                                                     const float* __restrict__ b0, float* __restrict__ out, int R) {
    __shared__ float4 sA4[128 * 16];  // 32 KB, quad index XOR-swizzled by (row&15)
    __shared__ float4 sM4[64 * 16];   // 16 KB
    int tid = threadIdx.x;
    int tr = tid & 15;   // row group: rows tr + 16*i
    int tj = tid >> 4;   // col group: cols 4*tj .. 4*tj+3
    int jc = blockIdx.y * 64;
    int tile0 = blockIdx.x * 128;
    if (tile0 >= R) return;
    int nrows = min(128, R - tile0);

    // stage M block [64 x 64] (cols jc..jc+63), linear layout
#pragma unroll
    for (int it = 0; it < 4; it++) {
        int f = tid + it * 256;  // f = k*16 + jq
        int k = f >> 4, jq = f & 15;
        sM4[f] = *(const float4*)(M + (size_t)k * OD + jc + 4 * jq);
    }
    // stage A tile [nrows x 64], coalesced global float4, swizzled LDS store
    {
        const float4* Ag = (const float4*)(A + (size_t)tile0 * 64);
#pragma unroll
        for (int it = 0; it < 8; it++) {
            int e = tid + it * 256;
            int r = e >> 4, q = e & 15;
            int srcq = (r < nrows) ? e : q;  // clamp OOB rows of partial tile to row 0
            sA4[(r << 4) | (q ^ (r & 15))] = Ag[srcq];
        }
    }
    __syncthreads();

    float4 b0v = *(const float4*)(b0 + jc + 4 * tj);
    float acc[8][4];
#pragma unroll
    for (int i = 0; i < 8; i++) { acc[i][0] = b0v.x; acc[i][1] = b0v.y; acc[i][2] = b0v.z; acc[i][3] = b0v.w; }

    for (int kq = 0; kq < 16; kq++) {
        float4 mf0 = sM4[(4 * kq + 0) * 16 + tj];
        float4 mf1 = sM4[(4 * kq + 1) * 16 + tj];
        float4 mf2 = sM4[(4 * kq + 2) * 16 + tj];
        float4 mf3 = sM4[(4 * kq + 3) * 16 + tj];
#pragma unroll
        for (int i = 0; i < 8; i++) {
            int row = tr + 16 * i;  // row & 15 == tr
            float4 af = sA4[(row << 4) | (kq ^ tr)];
            acc[i][0] = fmaf(af.x, mf0.x, acc[i][0]);
            acc[i][0] = fmaf(af.y, mf1.x, acc[i][0]);
            acc[i][0] = fmaf(af.z, mf2.x, acc[i][0]);
            acc[i][0] = fmaf(af.w, mf3.x, acc[i][0]);
            acc[i][1] = fmaf(af.x, mf0.y, acc[i][1]);
            acc[i][1] = fmaf(af.y, mf1.y, acc[i][1]);
            acc[i][1] = fmaf(af.z, mf2.y, acc[i][1]);
            acc[i][1] = fmaf(af.w, mf3.y, acc[i][1]);
            acc[i][2] = fmaf(af.x, mf0.z, acc[i][2]);
            acc[i][2] = fmaf(af.y, mf1.z, acc[i][2]);
            acc[i][2] = fmaf(af.z, mf2.z, acc[i][2]);
            acc[i][2] = fmaf(af.w, mf3.z, acc[i][2]);
            acc[i][3] = fmaf(af.x, mf0.w, acc[i][3]);
            acc[i][3] = fmaf(af.y, mf1.w, acc[i][3]);
            acc[i][3] = fmaf(af.z, mf2.w, acc[i][3]);
            acc[i][3] = fmaf(af.w, mf3.w, acc[i][3]);
        }
    }

#pragma unroll
    for (int i = 0; i < 8; i++) {
        int row = tr + 16 * i;
        if (row < nrows) {
            float4 t = {acc[i][0], acc[i][1], acc[i][2], acc[i][3]};
            *(float4*)(out + (size_t)(tile0 + row) * OD + jc + 4 * tj) = t;
        }
    }
}

// ---------------- fused message passing for BOTH convs; outputs head-mean hm ----------------
__global__ __launch_bounds__(128) void msg_fused(
    const float* __restrict__ xw_n, const float* __restrict__ a_sn, const float* __restrict__ a_dn,
    const float* __restrict__ xw_e, const float* __restrict__ a_se, const float* __restrict__ a_de,
    const int* __restrict__ rowptr, const int* __restrict__ ssrc,
    const float* __restrict__ bn, const float* __restrict__ be,
    float* __restrict__ hm_n, float* __restrict__ hm_e) {
    int n = blockIdx.x;
    int tid = threadIdx.x;
    int h = tid >> 6, c = tid & 63;
    __shared__ int s_src[MAXD];
    __shared__ float t_n[2][MAXD];
    __shared__ float t_e[2][MAXD];
    __shared__ float red[8];  // [conv*4 + {m0,m1,d0,d1}]
    __shared__ float hsh[2][128];

    int base = rowptr[n];
    int deg = rowptr[n + 1] - base;
    int degc = min(deg, MAXD);

    float adn0 = a_dn[n * 2 + 0], adn1 = a_dn[n * 2 + 1];
    float ade0 = a_de[n * 2 + 0], ade1 = a_de[n * 2 + 1];
    float2 asn_n = *(const float2*)(a_sn + (size_t)n * 2);
    float2 ase_n = *(const float2*)(a_se + (size_t)n * 2);
    float es_n0 = lrelu(asn_n.x + adn0), es_n1 = lrelu(asn_n.y + adn1);
    float es_e0 = lrelu(ase_n.x + ade0), es_e1 = lrelu(ase_n.y + ade1);

    // pass 1: cache src indices + leaky-relu logits (ONE gather over a_s)
    for (int i = tid; i < degc; i += 128) {
        int s = ssrc[base + i];
        s_src[i] = s;
        float2 an = *(const float2*)(a_sn + (size_t)s * 2);
        float2 ae = *(const float2*)(a_se + (size_t)s * 2);
        t_n[0][i] = lrelu(an.x + adn0);
        t_n[1][i] = lrelu(an.y + adn1);
        t_e[0][i] = lrelu(ae.x + ade0);
        t_e[1][i] = lrelu(ae.y + ade1);
    }
    __syncthreads();

    // reductions: wave 0 -> conv n, wave 1 -> conv e (both heads per wave)
    int w = tid >> 6;
    int lane = tid & 63;
    {
        const float(*tt)[MAXD] = w ? t_e : t_n;
        const float* asx = w ? a_se : a_sn;
        float ad0 = w ? ade0 : adn0, ad1 = w ? ade1 : adn1;
        float es0 = w ? es_e0 : es_n0, es1 = w ? es_e1 : es_n1;
        float m0 = es0, m1 = es1;
        for (int i = lane; i < degc; i += 64) { m0 = fmaxf(m0, tt[0][i]); m1 = fmaxf(m1, tt[1][i]); }
        for (int i = MAXD + lane; i < deg; i += 64) {
            int s = ssrc[base + i];
            float2 a = *(const float2*)(asx + (size_t)s * 2);
            m0 = fmaxf(m0, lrelu(a.x + ad0)); m1 = fmaxf(m1, lrelu(a.y + ad1));
        }
#pragma unroll
        for (int o = 1; o < 64; o <<= 1) { m0 = fmaxf(m0, __shfl_xor(m0, o)); m1 = fmaxf(m1, __shfl_xor(m1, o)); }
        // denominator: edge terms reduced across lanes; self term added ONCE after reduction
        float d0 = 0.f, d1 = 0.f;
        for (int i = lane; i < degc; i += 64) { d0 += __expf(tt[0][i] - m0); d1 += __expf(tt[1][i] - m1); }
        for (int i = MAXD + lane; i < deg; i += 64) {
            int s = ssrc[base + i];
            float2 a = *(const float2*)(asx + (size_t)s * 2);
            d0 += __expf(lrelu(a.x + ad0) - m0); d1 += __expf(lrelu(a.y + ad1) - m1);
        }
#pragma unroll
        for (int o = 1; o < 64; o <<= 1) { d0 += __shfl_xor(d0, o); d1 += __shfl_xor(d1, o); }
        d0 += __expf(es0 - m0);  // self-loop contribution, exactly once
        d1 += __expf(es1 - m1);
        if (lane == 0) { red[w * 4 + 0] = m0; red[w * 4 + 1] = m1; red[w * 4 + 2] = d0; red[w * 4 + 3] = d1; }
    }
    __syncthreads();

    // convert logits -> unnormalized weights in LDS (once)
    for (int i = tid; i < degc; i += 128) {
        t_n[0][i] = __expf(t_n[0][i] - red[0]);
        t_n[1][i] = __expf(t_n[1][i] - red[1]);
        t_e[0][i] = __expf(t_e[0][i] - red[4]);
        t_e[1][i] = __expf(t_e[1][i] - red[5]);
    }
    __syncthreads();

    float mn = red[h], dn_ = red[2 + h];
    float me = red[4 + h], de_ = red[6 + h];
    float accn = __expf((h ? es_n1 : es_n0) - mn) * xw_n[(size_t)n * 128 + h * 64 + c];
    float acce = __expf((h ? es_e1 : es_e0) - me) * xw_e[(size_t)n * 128 + h * 64 + c];
    for (int i = 0; i < degc; i++) {
        int s = s_src[i];
        float wn_ = t_n[h][i];
        float we_ = t_e[h][i];
        accn = fmaf(wn_, xw_n[(size_t)s * 128 + h * 64 + c], accn);
        acce = fmaf(we_, xw_e[(size_t)s * 128 + h * 64 + c], acce);
    }
    for (int i = MAXD; i < deg; i++) {
        int s = ssrc[base + i];
        float2 an = *(const float2*)(a_sn + (size_t)s * 2);
        float2 ae = *(const float2*)(a_se + (size_t)s * 2);
        float tn_ = lrelu(h ? (an.y + adn1) : (an.x + adn0));
        float te_ = lrelu(h ? (ae.y + ade1) : (ae.x + ade0));
        accn = fmaf(__expf(tn_ - mn), xw_n[(size_t)s * 128 + h * 64 + c], accn);
        acce = fmaf(__expf(te_ - me), xw_e[(size_t)s * 128 + h * 64 + c], acce);
    }
    hsh[0][tid] = accn / dn_;
    hsh[1][tid] = acce / de_;
    __syncthreads();
    if (tid < 64) {
        hm_n[(size_t)n * 64 + tid] = fmaf(0.5f, hsh[0][tid] + hsh[0][64 + tid], bn[tid]);
        hm_e[(size_t)n * 64 + tid] = fmaf(0.5f, hsh[1][tid] + hsh[1][64 + tid], be[tid]);
    }
}

extern "C" void kernel_launch(void* const* d_in, const int* in_sizes, int n_in,
                              void* d_out, int out_size, void* d_ws, size_t ws_size,
                              hipStream_t stream) {
    const float* x   = (const float*)d_in[0];
    const float* xe  = (const float*)d_in[1];
    const int*   ei  = (const int*)d_in[2];
    const float* Wn  = (const float*)d_in[3];
    const float* asn = (const float*)d_in[4];
    const float* adn = (const float*)d_in[5];
    const float* bn  = (const float*)d_in[6];
    const float* We  = (const float*)d_in[7];
    const float* ase = (const float*)d_in[8];
    const float* ade = (const float*)d_in[9];
    const float* be  = (const float*)d_in[10];
    const float* Wdx = (const float*)d_in[11];
    const float* bdx = (const float*)d_in[12];
    const float* Wde = (const float*)d_in[13];
    const float* bde = (const float*)d_in[14];

    const int N  = in_sizes[0] / 128;  // 50000
    const int NE = in_sizes[1] / 64;   // 800000
    const int E  = in_sizes[2] / 2;    // 800000
    const int* src = ei;
    const int* dst = ei + E;

    char* wsb = (char*)d_ws;
    size_t off = 0;
    auto alloc = [&](size_t bytes) -> void* {
        void* p = wsb + off;
        off += (bytes + 255) & ~(size_t)255;
        return p;
    };
    float* xw_n = (float*)alloc((size_t)N * 128 * 4);
    float* a_sn = (float*)alloc((size_t)N * 2 * 4);
    float* a_dn = (float*)alloc((size_t)N * 2 * 4);
    float* xw_e = (float*)alloc((size_t)N * 128 * 4);
    float* a_se = (float*)alloc((size_t)N * 2 * 4);
    float* a_de = (float*)alloc((size_t)N * 2 * 4);
    float* hm_n = (float*)alloc((size_t)N * 64 * 4);
    float* hm_e = (float*)alloc((size_t)N * 64 * 4);
    float* Mt   = (float*)alloc((size_t)64 * 64 * 4);
    float* b0t  = (float*)alloc((size_t)64 * 4);
    int* cnt    = (int*)alloc((size_t)(N + 1) * 4);
    int* rowptr = (int*)alloc((size_t)(N + 1) * 4);
    int* cursor = (int*)alloc((size_t)(N + 1) * 4);
    int* ssrc   = (int*)alloc((size_t)E * 4);

    float* x_rec = (float*)d_out;
    float* e_rec = (float*)d_out + (size_t)N * 128;

    // CSR build (shared by both convs)
    hipMemsetAsync(cnt, 0, (size_t)N * 4, stream);
    count_kernel<<<(E + 255) / 256, 256, 0, stream>>>(dst, cnt, E);
    scan_kernel<<<1, 1024, 0, stream>>>(cnt, rowptr, N);
    hipMemcpyAsync(cursor, rowptr, (size_t)N * 4, hipMemcpyDeviceToDevice, stream);
    scatter_kernel<<<(E + 255) / 256, 256, 0, stream>>>(src, dst, cursor, ssrc, E);

    // Fold tail affine map
    fold_kernel<<<65, 64, 0, stream>>>(We, Wde, be, bde, Mt, b0t);

    // Encoders (register-tiled, coalesced; one head per blockIdx.y; fused a_s/a_d)
    enc_tiled<128><<<dim3((N + 127) / 128, 2), 256, 0, stream>>>(x, Wn, asn, adn, xw_n, a_sn, a_dn, N);
    enc_tiled<64><<<dim3((N + 127) / 128, 2), 256, 0, stream>>>(xe, We, ase, ade, xw_e, a_se, a_de, N);

    // Tail: 750k self-loop-only rows, folded to a single affine map (register-tiled GEMM)
    {
        int R = NE - N;
        rowmap_kernel<64><<<dim3((R + 127) / 128, 1), 256, 0, stream>>>(
            xe + (size_t)N * 64, Mt, b0t, e_rec + (size_t)N * 64, R);
    }

    // Fused message passing for both convs -> head-mean hidden states
    msg_fused<<<N, 128, 0, stream>>>(xw_n, a_sn, a_dn, xw_e, a_se, a_de, rowptr, ssrc, bn, be, hm_n, hm_e);

    // Decoders (register-tiled GEMM; OD=128 splits column halves across gridDim.y)
    rowmap_kernel<128><<<dim3((N + 127) / 128, 2), 256, 0, stream>>>(hm_n, Wdx, bdx, x_rec, N);
    rowmap_kernel<64><<<dim3((N + 127) / 128, 1), 256, 0, stream>>>(hm_e, Wde, bde, e_rec, N);
}

// Round 9
// 750.416 us; speedup vs baseline: 3.7641x; 1.0542x over previous
//
#include <hip/hip_runtime.h>
#include <hip/hip_bf16.h>

// H=2, C=64, IN=128, EIN=64, N=50000, E=800000
constexpr int MAXD = 512;

__device__ __forceinline__ float lrelu(float v) { return v >= 0.f ? v : 0.2f * v; }

// ---------------- fused CSR-count + fold (independent work, one dispatch) ----------------
__global__ __launch_bounds__(256) void count_fold_kernel(
    const int* __restrict__ dst, int* __restrict__ cnt, int E, int nbCount,
    const float* __restrict__ We, const float* __restrict__ Wde,
    const float* __restrict__ be, const float* __restrict__ bde,
    float* __restrict__ M, float* __restrict__ b0) {
    int b = blockIdx.x;
    if (b < nbCount) {
        int e = b * 256 + threadIdx.x;
        if (e < E) atomicAdd(&cnt[dst[e]], 1);
    } else {
        int k = b - nbCount;  // 0..64; block 64 does b0
        int j = threadIdx.x;
        if (j >= 64) return;
        if (k < 64) {
            float s = 0.f;
            for (int c = 0; c < 64; c++)
                s = fmaf(0.5f * (We[k * 128 + c] + We[k * 128 + 64 + c]), Wde[c * 64 + j], s);
            M[k * 64 + j] = s;
        } else {
            float s = bde[j];
            for (int c = 0; c < 64; c++) s = fmaf(be[c], Wde[c * 64 + j], s);
            b0[j] = s;
        }
    }
}

__global__ __launch_bounds__(1024) void scan_kernel(const int* __restrict__ cnt, int* __restrict__ rowptr, int n) {
    __shared__ int part[1024];
    int t = threadIdx.x;
    int CH = (n + 1023) / 1024;
    int base = t * CH;
    int local = 0;
    for (int i = 0; i < CH; i++) { int idx = base + i; if (idx < n) local += cnt[idx]; }
    part[t] = local;
    __syncthreads();
    for (int o = 1; o < 1024; o <<= 1) {
        int v = (t >= o) ? part[t - o] : 0;
        __syncthreads();
        part[t] += v;
        __syncthreads();
    }
    int run = part[t] - local;  // exclusive prefix
    for (int i = 0; i < CH; i++) {
        int idx = base + i;
        if (idx < n) { rowptr[idx] = run; run += cnt[idx]; }
    }
    if (t == 1023) rowptr[n] = run;
}

__global__ void scatter_kernel(const int* __restrict__ src, const int* __restrict__ dst,
                               int* __restrict__ cursor, int* __restrict__ ssrc, int E) {
    int e = blockIdx.x * blockDim.x + threadIdx.x;
    if (e < E) {
        int pos = atomicAdd(&cursor[dst[e]], 1);
        ssrc[pos] = src[e];
    }
}

// ---------------- encoder body (v5 register-tiled structure + fused a_s/a_d) ----------------
template <int K>
__device__ __forceinline__ void enc_body(const float* __restrict__ X, const float* __restrict__ W,
                                         const float* __restrict__ avs, const float* __restrict__ avd,
                                         float* __restrict__ xw, float* __restrict__ a_s,
                                         float* __restrict__ a_d, int Nn, int bx, int h,
                                         float4* sA4, float4* sM4) {
    int tid = threadIdx.x;
    int tr = tid & 15;   // rows tr + 16*i
    int tj = tid >> 4;   // cols 4*tj .. 4*tj+3
    int jc = h * 64;
    int tile0 = bx * 128;
    if (tile0 >= Nn) return;
    int nrows = min(128, Nn - tile0);

    float acc[8][4];
#pragma unroll
    for (int i = 0; i < 8; i++) { acc[i][0] = 0.f; acc[i][1] = 0.f; acc[i][2] = 0.f; acc[i][3] = 0.f; }

    for (int kc = 0; kc < K; kc += 64) {
        if (kc) __syncthreads();  // previous slab fully consumed before restage
#pragma unroll
        for (int it = 0; it < 4; it++) {
            int f = tid + it * 256;  // f = k*16 + jq
            int k = f >> 4, jq = f & 15;
            sM4[f] = *(const float4*)(W + (size_t)(kc + k) * 128 + jc + 4 * jq);
        }
#pragma unroll
        for (int it = 0; it < 8; it++) {
            int e = tid + it * 256;
            int r = e >> 4, q = e & 15;
            int rs = (r < nrows) ? r : 0;
            sA4[(r << 4) | (q ^ (r & 15))] = *(const float4*)(X + (size_t)(tile0 + rs) * K + kc + 4 * q);
        }
        __syncthreads();
        for (int kq = 0; kq < 16; kq++) {
            float4 mf0 = sM4[(4 * kq + 0) * 16 + tj];
            float4 mf1 = sM4[(4 * kq + 1) * 16 + tj];
            float4 mf2 = sM4[(4 * kq + 2) * 16 + tj];
            float4 mf3 = sM4[(4 * kq + 3) * 16 + tj];
#pragma unroll
            for (int i = 0; i < 8; i++) {
                int row = tr + 16 * i;
                float4 af = sA4[(row << 4) | (kq ^ tr)];
                acc[i][0] = fmaf(af.x, mf0.x, acc[i][0]);
                acc[i][0] = fmaf(af.y, mf1.x, acc[i][0]);
                acc[i][0] = fmaf(af.z, mf2.x, acc[i][0]);
                acc[i][0] = fmaf(af.w, mf3.x, acc[i][0]);
                acc[i][1] = fmaf(af.x, mf0.y, acc[i][1]);
                acc[i][1] = fmaf(af.y, mf1.y, acc[i][1]);
                acc[i][1] = fmaf(af.z, mf2.y, acc[i][1]);
                acc[i][1] = fmaf(af.w, mf3.y, acc[i][1]);
                acc[i][2] = fmaf(af.x, mf0.z, acc[i][2]);
                acc[i][2] = fmaf(af.y, mf1.z, acc[i][2]);
                acc[i][2] = fmaf(af.z, mf2.z, acc[i][2]);
                acc[i][2] = fmaf(af.w, mf3.z, acc[i][2]);
                acc[i][3] = fmaf(af.x, mf0.w, acc[i][3]);
                acc[i][3] = fmaf(af.y, mf1.w, acc[i][3]);
                acc[i][3] = fmaf(af.z, mf2.w, acc[i][3]);
                acc[i][3] = fmaf(af.w, mf3.w, acc[i][3]);
            }
        }
    }

#pragma unroll
    for (int i = 0; i < 8; i++) {
        int row = tr + 16 * i;
        if (row < nrows) {
            float4 t = {acc[i][0], acc[i][1], acc[i][2], acc[i][3]};
            *(float4*)(xw + (size_t)(tile0 + row) * 128 + jc + 4 * tj) = t;
        }
    }

    // fused a_s/a_d: per-thread 4-col partials + padded-LDS 16-way tj-reduction (stride 17)
    float4 vs = *(const float4*)(avs + jc + 4 * tj);
    float4 vd = *(const float4*)(avd + jc + 4 * tj);
    __syncthreads();
    float* red = (float*)sA4;
#pragma unroll
    for (int i = 0; i < 8; i++) {
        int row = tr + 16 * i;
        float ps = acc[i][0] * vs.x + acc[i][1] * vs.y + acc[i][2] * vs.z + acc[i][3] * vs.w;
        float pd = acc[i][0] * vd.x + acc[i][1] * vd.y + acc[i][2] * vd.z + acc[i][3] * vd.w;
        red[row * 17 + tj] = ps;
        red[4096 + row * 17 + tj] = pd;
    }
    __syncthreads();
    if (tid < 128 && tid < nrows) {
        float ss = 0.f, sd = 0.f;
#pragma unroll
        for (int t = 0; t < 16; t++) { ss += red[tid * 17 + t]; sd += red[4096 + tid * 17 + t]; }
        a_s[(size_t)(tile0 + tid) * 2 + h] = ss;
        a_d[(size_t)(tile0 + tid) * 2 + h] = sd;
    }
}

// both encoders in one dispatch: z=0 node conv (K=128), z=1 edge conv (K=64)
__global__ __launch_bounds__(256) void enc_both(
    const float* __restrict__ x, const float* __restrict__ Wn, const float* __restrict__ asn,
    const float* __restrict__ adn, float* __restrict__ xw_n, float* __restrict__ a_sn, float* __restrict__ a_dn,
    const float* __restrict__ xe, const float* __restrict__ We, const float* __restrict__ ase,
    const float* __restrict__ ade, float* __restrict__ xw_e, float* __restrict__ a_se, float* __restrict__ a_de,
    int N) {
    __shared__ float4 sA4[128 * 16];  // 32 KB
    __shared__ float4 sM4[64 * 16];   // 16 KB
    if (blockIdx.z == 0)
        enc_body<128>(x, Wn, asn, adn, xw_n, a_sn, a_dn, N, blockIdx.x, blockIdx.y, sA4, sM4);
    else
        enc_body<64>(xe, We, ase, ade, xw_e, a_se, a_de, N, blockIdx.x, blockIdx.y, sA4, sM4);
}

// ---------------- row-map body (v5 register-tiled GEMM, verified) ----------------
template <int OD>
__device__ __forceinline__ void rowmap_body(const float* __restrict__ A, const float* __restrict__ M,
                                            const float* __restrict__ b0, float* __restrict__ out, int R,
                                            int bx, int by, float4* sA4, float4* sM4) {
    int tid = threadIdx.x;
    int tr = tid & 15;
    int tj = tid >> 4;
    int jc = by * 64;
    int tile0 = bx * 128;
    if (tile0 >= R) return;
    int nrows = min(128, R - tile0);

#pragma unroll
    for (int it = 0; it < 4; it++) {
        int f = tid + it * 256;  // f = k*16 + jq
        int k = f >> 4, jq = f & 15;
        sM4[f] = *(const float4*)(M + (size_t)k * OD + jc + 4 * jq);
    }
    {
        const float4* Ag = (const float4*)(A + (size_t)tile0 * 64);
#pragma unroll
        for (int it = 0; it < 8; it++) {
            int e = tid + it * 256;
            int r = e >> 4, q = e & 15;
            int srcq = (r < nrows) ? e : q;  // clamp OOB rows of partial tile to row 0
            sA4[(r << 4) | (q ^ (r & 15))] = Ag[srcq];
        }
    }
    __syncthreads();

    float4 b0v = *(const float4*)(b0 + jc + 4 * tj);
    float acc[8][4];
#pragma unroll
    for (int i = 0; i < 8; i++) { acc[i][0] = b0v.x; acc[i][1] = b0v.y; acc[i][2] = b0v.z; acc[i][3] = b0v.w; }

    for (int kq = 0; kq < 16; kq++) {
        float4 mf0 = sM4[(4 * kq + 0) * 16 + tj];
        float4 mf1 = sM4[(4 * kq + 1) * 16 + tj];
        float4 mf2 = sM4[(4 * kq + 2) * 16 + tj];
        float4 mf3 = sM4[(4 * kq + 3) * 16 + tj];
#pragma unroll
        for (int i = 0; i < 8; i++) {
            int row = tr + 16 * i;
            float4 af = sA4[(row << 4) | (kq ^ tr)];
            acc[i][0] = fmaf(af.x, mf0.x, acc[i][0]);
            acc[i][0] = fmaf(af.y, mf1.x, acc[i][0]);
            acc[i][0] = fmaf(af.z, mf2.x, acc[i][0]);
            acc[i][0] = fmaf(af.w, mf3.x, acc[i][0]);
            acc[i][1] = fmaf(af.x, mf0.y, acc[i][1]);
            acc[i][1] = fmaf(af.y, mf1.y, acc[i][1]);
            acc[i][1] = fmaf(af.z, mf2.y, acc[i][1]);
            acc[i][1] = fmaf(af.w, mf3.y, acc[i][1]);
            acc[i][2] = fmaf(af.x, mf0.z, acc[i][2]);
            acc[i][2] = fmaf(af.y, mf1.z, acc[i][2]);
            acc[i][2] = fmaf(af.z, mf2.z, acc[i][2]);
            acc[i][2] = fmaf(af.w, mf3.z, acc[i][2]);
            acc[i][3] = fmaf(af.x, mf0.w, acc[i][3]);
            acc[i][3] = fmaf(af.y, mf1.w, acc[i][3]);
            acc[i][3] = fmaf(af.z, mf2.w, acc[i][3]);
            acc[i][3] = fmaf(af.w, mf3.w, acc[i][3]);
        }
    }

#pragma unroll
    for (int i = 0; i < 8; i++) {
        int row = tr + 16 * i;
        if (row < nrows) {
            float4 t = {acc[i][0], acc[i][1], acc[i][2], acc[i][3]};
            *(float4*)(out + (size_t)(tile0 + row) * OD + jc + 4 * tj) = t;
        }
    }
}

// tail + dec128 + dec64 in ONE dispatch: the small decoders co-schedule with (and hide
// under) the HBM-bound 5860-block tail stream; two launch gaps removed.
__global__ __launch_bounds__(256) void rowmaps_all(
    const float* __restrict__ xeTail, const float* __restrict__ Mt, const float* __restrict__ b0t,
    float* __restrict__ outTail, int Rtail, int nbTail,
    const float* __restrict__ hm_n, const float* __restrict__ Wdx, const float* __restrict__ bdx,
    float* __restrict__ x_rec,
    const float* __restrict__ hm_e, const float* __restrict__ Wde, const float* __restrict__ bde,
    float* __restrict__ e_rec, int N, int nbDec) {
    __shared__ float4 sA4[128 * 16];  // 32 KB
    __shared__ float4 sM4[64 * 16];   // 16 KB
    int b = blockIdx.x;
    if (b < nbTail) {
        rowmap_body<64>(xeTail, Mt, b0t, outTail, Rtail, b, 0, sA4, sM4);
    } else if (b < nbTail + 2 * nbDec) {
        int bb = b - nbTail;  // bb>>1 = row tile, bb&1 = column half
        rowmap_body<128>(hm_n, Wdx, bdx, x_rec, N, bb >> 1, bb & 1, sA4, sM4);
    } else {
        rowmap_body<64>(hm_e, Wde, bde, e_rec, N, b - nbTail - 2 * nbDec, 0, sA4, sM4);
    }
}

// ---------------- fused message passing for BOTH convs; outputs head-mean hm ----------------
__global__ __launch_bounds__(128) void msg_fused(
    const float* __restrict__ xw_n, const float* __restrict__ a_sn, const float* __restrict__ a_dn,
    const float* __restrict__ xw_e, const float* __restrict__ a_se, const float* __restrict__ a_de,
    const int* __restrict__ rowptr, const int* __restrict__ ssrc,
    const float* __restrict__ bn, const float* __restrict__ be,
    float* __restrict__ hm_n, float* __restrict__ hm_e) {
    int n = blockIdx.x;
    int tid = threadIdx.x;
    int h = tid >> 6, c = tid & 63;
    __shared__ int s_src[MAXD];
    __shared__ float t_n[2][MAXD];
    __shared__ float t_e[2][MAXD];
    __shared__ float red[8];  // [conv*4 + {m0,m1,d0,d1}]
    __shared__ float hsh[2][128];

    int base = rowptr[n];
    int deg = rowptr[n + 1] - base;
    int degc = min(deg, MAXD);

    float adn0 = a_dn[n * 2 + 0], adn1 = a_dn[n * 2 + 1];
    float ade0 = a_de[n * 2 + 0], ade1 = a_de[n * 2 + 1];
    float2 asn_n = *(const float2*)(a_sn + (size_t)n * 2);
    float2 ase_n = *(const float2*)(a_se + (size_t)n * 2);
    float es_n0 = lrelu(asn_n.x + adn0), es_n1 = lrelu(asn_n.y + adn1);
    float es_e0 = lrelu(ase_n.x + ade0), es_e1 = lrelu(ase_n.y + ade1);

    // pass 1: cache src indices + leaky-relu logits (ONE gather over a_s)
    for (int i = tid; i < degc; i += 128) {
        int s = ssrc[base + i];
        s_src[i] = s;
        float2 an = *(const float2*)(a_sn + (size_t)s * 2);
        float2 ae = *(const float2*)(a_se + (size_t)s * 2);
        t_n[0][i] = lrelu(an.x + adn0);
        t_n[1][i] = lrelu(an.y + adn1);
        t_e[0][i] = lrelu(ae.x + ade0);
        t_e[1][i] = lrelu(ae.y + ade1);
    }
    __syncthreads();

    // reductions: wave 0 -> conv n, wave 1 -> conv e (both heads per wave)
    int w = tid >> 6;
    int lane = tid & 63;
    {
        const float(*tt)[MAXD] = w ? t_e : t_n;
        const float* asx = w ? a_se : a_sn;
        float ad0 = w ? ade0 : adn0, ad1 = w ? ade1 : adn1;
        float es0 = w ? es_e0 : es_n0, es1 = w ? es_e1 : es_n1;
        float m0 = es0, m1 = es1;
        for (int i = lane; i < degc; i += 64) { m0 = fmaxf(m0, tt[0][i]); m1 = fmaxf(m1, tt[1][i]); }
        for (int i = MAXD + lane; i < deg; i += 64) {
            int s = ssrc[base + i];
            float2 a = *(const float2*)(asx + (size_t)s * 2);
            m0 = fmaxf(m0, lrelu(a.x + ad0)); m1 = fmaxf(m1, lrelu(a.y + ad1));
        }
#pragma unroll
        for (int o = 1; o < 64; o <<= 1) { m0 = fmaxf(m0, __shfl_xor(m0, o)); m1 = fmaxf(m1, __shfl_xor(m1, o)); }
        // denominator: edge terms reduced across lanes; self term added ONCE after reduction
        float d0 = 0.f, d1 = 0.f;
        for (int i = lane; i < degc; i += 64) { d0 += __expf(tt[0][i] - m0); d1 += __expf(tt[1][i] - m1); }
        for (int i = MAXD + lane; i < deg; i += 64) {
            int s = ssrc[base + i];
            float2 a = *(const float2*)(asx + (size_t)s * 2);
            d0 += __expf(lrelu(a.x + ad0) - m0); d1 += __expf(lrelu(a.y + ad1) - m1);
        }
#pragma unroll
        for (int o = 1; o < 64; o <<= 1) { d0 += __shfl_xor(d0, o); d1 += __shfl_xor(d1, o); }
        d0 += __expf(es0 - m0);  // self-loop contribution, exactly once
        d1 += __expf(es1 - m1);
        if (lane == 0) { red[w * 4 + 0] = m0; red[w * 4 + 1] = m1; red[w * 4 + 2] = d0; red[w * 4 + 3] = d1; }
    }
    __syncthreads();

    // convert logits -> unnormalized weights in LDS (once)
    for (int i = tid; i < degc; i += 128) {
        t_n[0][i] = __expf(t_n[0][i] - red[0]);
        t_n[1][i] = __expf(t_n[1][i] - red[1]);
        t_e[0][i] = __expf(t_e[0][i] - red[4]);
        t_e[1][i] = __expf(t_e[1][i] - red[5]);
    }
    __syncthreads();

    float mn = red[h], dn_ = red[2 + h];
    float me = red[4 + h], de_ = red[6 + h];
    float accn = __expf((h ? es_n1 : es_n0) - mn) * xw_n[(size_t)n * 128 + h * 64 + c];
    float acce = __expf((h ? es_e1 : es_e0) - me) * xw_e[(size_t)n * 128 + h * 64 + c];
    for (int i = 0; i < degc; i++) {
        int s = s_src[i];
        float wn_ = t_n[h][i];
        float we_ = t_e[h][i];
        accn = fmaf(wn_, xw_n[(size_t)s * 128 + h * 64 + c], accn);
        acce = fmaf(we_, xw_e[(size_t)s * 128 + h * 64 + c], acce);
    }
    for (int i = MAXD; i < deg; i++) {
        int s = ssrc[base + i];
        float2 an = *(const float2*)(a_sn + (size_t)s * 2);
        float2 ae = *(const float2*)(a_se + (size_t)s * 2);
        float tn_ = lrelu(h ? (an.y + adn1) : (an.x + adn0));
        float te_ = lrelu(h ? (ae.y + ade1) : (ae.x + ade0));
        accn = fmaf(__expf(tn_ - mn), xw_n[(size_t)s * 128 + h * 64 + c], accn);
        acce = fmaf(__expf(te_ - me), xw_e[(size_t)s * 128 + h * 64 + c], acce);
    }
    hsh[0][tid] = accn / dn_;
    hsh[1][tid] = acce / de_;
    __syncthreads();
    if (tid < 64) {
        hm_n[(size_t)n * 64 + tid] = fmaf(0.5f, hsh[0][tid] + hsh[0][64 + tid], bn[tid]);
        hm_e[(size_t)n * 64 + tid] = fmaf(0.5f, hsh[1][tid] + hsh[1][64 + tid], be[tid]);
    }
}

extern "C" void kernel_launch(void* const* d_in, const int* in_sizes, int n_in,
                              void* d_out, int out_size, void* d_ws, size_t ws_size,
                              hipStream_t stream) {
    const float* x   = (const float*)d_in[0];
    const float* xe  = (const float*)d_in[1];
    const int*   ei  = (const int*)d_in[2];
    const float* Wn  = (const float*)d_in[3];
    const float* asn = (const float*)d_in[4];
    const float* adn = (const float*)d_in[5];
    const float* bn  = (const float*)d_in[6];
    const float* We  = (const float*)d_in[7];
    const float* ase = (const float*)d_in[8];
    const float* ade = (const float*)d_in[9];
    const float* be  = (const float*)d_in[10];
    const float* Wdx = (const float*)d_in[11];
    const float* bdx = (const float*)d_in[12];
    const float* Wde = (const float*)d_in[13];
    const float* bde = (const float*)d_in[14];

    const int N  = in_sizes[0] / 128;  // 50000
    const int NE = in_sizes[1] / 64;   // 800000
    const int E  = in_sizes[2] / 2;    // 800000
    const int* src = ei;
    const int* dst = ei + E;

    char* wsb = (char*)d_ws;
    size_t off = 0;
    auto alloc = [&](size_t bytes) -> void* {
        void* p = wsb + off;
        off += (bytes + 255) & ~(size_t)255;
        return p;
    };
    float* xw_n = (float*)alloc((size_t)N * 128 * 4);
    float* a_sn = (float*)alloc((size_t)N * 2 * 4);
    float* a_dn = (float*)alloc((size_t)N * 2 * 4);
    float* xw_e = (float*)alloc((size_t)N * 128 * 4);
    float* a_se = (float*)alloc((size_t)N * 2 * 4);
    float* a_de = (float*)alloc((size_t)N * 2 * 4);
    float* hm_n = (float*)alloc((size_t)N * 64 * 4);
    float* hm_e = (float*)alloc((size_t)N * 64 * 4);
    float* Mt   = (float*)alloc((size_t)64 * 64 * 4);
    float* b0t  = (float*)alloc((size_t)64 * 4);
    int* cnt    = (int*)alloc((size_t)(N + 1) * 4);
    int* rowptr = (int*)alloc((size_t)(N + 1) * 4);
    int* cursor = (int*)alloc((size_t)(N + 1) * 4);
    int* ssrc   = (int*)alloc((size_t)E * 4);

    float* x_rec = (float*)d_out;
    float* e_rec = (float*)d_out + (size_t)N * 128;

    // CSR count + fold (fused, independent work)
    hipMemsetAsync(cnt, 0, (size_t)N * 4, stream);
    int nbCount = (E + 255) / 256;
    count_fold_kernel<<<nbCount + 65, 256, 0, stream>>>(dst, cnt, E, nbCount, We, Wde, be, bde, Mt, b0t);
    scan_kernel<<<1, 1024, 0, stream>>>(cnt, rowptr, N);
    hipMemcpyAsync(cursor, rowptr, (size_t)N * 4, hipMemcpyDeviceToDevice, stream);
    scatter_kernel<<<(E + 255) / 256, 256, 0, stream>>>(src, dst, cursor, ssrc, E);

    // Both encoders in one dispatch (z=0: node conv K=128, z=1: edge conv K=64)
    enc_both<<<dim3((N + 127) / 128, 2, 2), 256, 0, stream>>>(
        x, Wn, asn, adn, xw_n, a_sn, a_dn,
        xe, We, ase, ade, xw_e, a_se, a_de, N);

    // Fused message passing for both convs -> head-mean hidden states
    msg_fused<<<N, 128, 0, stream>>>(xw_n, a_sn, a_dn, xw_e, a_se, a_de, rowptr, ssrc, bn, be, hm_n, hm_e);

    // Tail (750k folded rows) + both decoders in ONE dispatch; decoders hide under tail stream
    {
        int Rtail = NE - N;
        int nbTail = (Rtail + 127) / 128;
        int nbDec = (N + 127) / 128;
        rowmaps_all<<<nbTail + 3 * nbDec, 256, 0, stream>>>(
            xe + (size_t)N * 64, Mt, b0t, e_rec + (size_t)N * 64, Rtail, nbTail,
            hm_n, Wdx, bdx, x_rec,
            hm_e, Wde, bde, e_rec, N, nbDec);
    }
}